// Round 5
// baseline (259.135 us; speedup 1.0000x reference)
//
#include <hip/hip_runtime.h>
#include <hip/hip_bf16.h>
#include <cstdint>
#include <cstddef>

#define N_B 4
#define D_F 512
#define L_S 2048
#define H_N 8
#define DH  64
#define C3  (3*D_F)   // 1536

typedef __attribute__((ext_vector_type(8))) short short8;
typedef __attribute__((ext_vector_type(4))) float f32x4;

__device__ __forceinline__ unsigned int pk_bf16(float a, float b) {
    __hip_bfloat162 h = __float22bfloat162_rn(float2{a, b});
    union { __hip_bfloat162 h; unsigned int u; } cv;
    cv.h = h;
    return cv.u;
}
__device__ __forceinline__ unsigned short bf16_rn(float f) {
    union { float f; unsigned int u; } c; c.f = f;
    unsigned int r = c.u + 0x7FFF + ((c.u >> 16) & 1);
    return (unsigned short)(r >> 16);
}
__device__ __forceinline__ float bf16_f(unsigned short h) {
    union { unsigned int u; float f; } c; c.u = ((unsigned int)h) << 16;
    return c.f;
}

// async global->LDS, 16B per lane; lds base must be wave-uniform.
__device__ __forceinline__ void gll16(const unsigned short* g, unsigned short* l) {
    __builtin_amdgcn_global_load_lds(
        (const __attribute__((address_space(1))) unsigned int*)g,
        (__attribute__((address_space(3))) unsigned int*)l,
        16, 0, 0);
}

// ---------------------------------------------------------------------------
// Split fp32 -> bf16 hi + bf16 lo
// ---------------------------------------------------------------------------
__global__ __launch_bounds__(256) void cvt_split(const float* __restrict__ src,
                                                 unsigned short* __restrict__ hi,
                                                 unsigned short* __restrict__ lo,
                                                 int n4) {
    int i = blockIdx.x * 256 + threadIdx.x;
    if (i >= n4) return;
    float4 v = ((const float4*)src)[i];
    ushort4 h, l;
    h.x = bf16_rn(v.x); l.x = bf16_rn(v.x - bf16_f(h.x));
    h.y = bf16_rn(v.y); l.y = bf16_rn(v.y - bf16_f(h.y));
    h.z = bf16_rn(v.z); l.z = bf16_rn(v.z - bf16_f(h.z));
    h.w = bf16_rn(v.w); l.w = bf16_rn(v.w - bf16_f(h.w));
    ((ushort4*)hi)[i] = h;
    ((ushort4*)lo)[i] = l;
}

// ---------------------------------------------------------------------------
// MFMA GEMM (unchanged): Y[n][o][l] = sum_c W[o][c] * X[n][c][l]
// ---------------------------------------------------------------------------
template<int SPLIT, int OUT_BF16>
__global__ __launch_bounds__(256) void gemm_mfma(const unsigned short* __restrict__ Whi,
                                                 const unsigned short* __restrict__ Wlo,
                                                 const unsigned short* __restrict__ Xhi,
                                                 const unsigned short* __restrict__ Xlo,
                                                 void* __restrict__ Y,
                                                 int O, int C) {
    __shared__ unsigned short Wt[SPLIT ? 2 : 1][4][128 * 8];
    __shared__ unsigned short Xt[SPLIT ? 2 : 1][4][128 * 8];

    const int tid  = threadIdx.x;
    const int lane = tid & 63;
    const int w    = tid >> 6;
    const int g    = lane >> 4;
    const int c    = lane & 15;
    const int wr   = (w >> 1) * 64;
    const int wc   = (w & 1) * 64;
    const int l0   = blockIdx.x * 128;
    const int o0   = blockIdx.y * 128;
    const int n    = blockIdx.z;

    const unsigned short* Xn_hi = Xhi + (size_t)n * C * L_S;
    const unsigned short* Xn_lo = SPLIT ? (Xlo + (size_t)n * C * L_S) : nullptr;

    f32x4 acc[4][4];
#pragma unroll
    for (int mt = 0; mt < 4; ++mt)
#pragma unroll
        for (int nt = 0; nt < 4; ++nt) acc[mt][nt] = (f32x4){0.f, 0.f, 0.f, 0.f};

    for (int c0 = 0; c0 < C; c0 += 32) {
        __syncthreads();
#pragma unroll
        for (int t = tid; t < 512; t += 256) {
            int o = t & 127, cp = t >> 7;
            size_t off = (size_t)(o0 + o) * C + c0 + cp * 8;
            *(uint4*)&Wt[0][cp][o * 8] = *(const uint4*)(Whi + off);
            if (SPLIT) *(uint4*)&Wt[1][cp][o * 8] = *(const uint4*)(Wlo + off);
        }
#pragma unroll
        for (int t = tid; t < 512; t += 256) {
            int l = t & 127, cp = t >> 7;
            const unsigned short* src = Xn_hi + (size_t)(c0 + cp * 8) * L_S + l0 + l;
            short8 v;
#pragma unroll
            for (int i = 0; i < 8; ++i) v[i] = (short)src[(size_t)i * L_S];
            *(short8*)&Xt[0][cp][l * 8] = v;
            if (SPLIT) {
                const unsigned short* srcl = Xn_lo + (size_t)(c0 + cp * 8) * L_S + l0 + l;
                short8 vl;
#pragma unroll
                for (int i = 0; i < 8; ++i) vl[i] = (short)srcl[(size_t)i * L_S];
                *(short8*)&Xt[1][cp][l * 8] = vl;
            }
        }
        __syncthreads();

        short8 a0[4], b0[4];
#pragma unroll
        for (int mt = 0; mt < 4; ++mt) a0[mt] = *(short8*)&Wt[0][g][(wr + mt * 16 + c) * 8];
#pragma unroll
        for (int nt = 0; nt < 4; ++nt) b0[nt] = *(short8*)&Xt[0][g][(wc + nt * 16 + c) * 8];

        if (SPLIT) {
            short8 a1[4], b1[4];
#pragma unroll
            for (int mt = 0; mt < 4; ++mt) a1[mt] = *(short8*)&Wt[1][g][(wr + mt * 16 + c) * 8];
#pragma unroll
            for (int nt = 0; nt < 4; ++nt) b1[nt] = *(short8*)&Xt[1][g][(wc + nt * 16 + c) * 8];
#pragma unroll
            for (int mt = 0; mt < 4; ++mt)
#pragma unroll
                for (int nt = 0; nt < 4; ++nt) {
                    acc[mt][nt] = __builtin_amdgcn_mfma_f32_16x16x32_bf16(a0[mt], b0[nt], acc[mt][nt], 0, 0, 0);
                    acc[mt][nt] = __builtin_amdgcn_mfma_f32_16x16x32_bf16(a0[mt], b1[nt], acc[mt][nt], 0, 0, 0);
                    acc[mt][nt] = __builtin_amdgcn_mfma_f32_16x16x32_bf16(a1[mt], b0[nt], acc[mt][nt], 0, 0, 0);
                }
        } else {
#pragma unroll
            for (int mt = 0; mt < 4; ++mt)
#pragma unroll
                for (int nt = 0; nt < 4; ++nt)
                    acc[mt][nt] = __builtin_amdgcn_mfma_f32_16x16x32_bf16(a0[mt], b0[nt], acc[mt][nt], 0, 0, 0);
        }
    }

#pragma unroll
    for (int mt = 0; mt < 4; ++mt) {
#pragma unroll
        for (int r = 0; r < 4; ++r) {
            int oo = o0 + wr + mt * 16 + g * 4 + r;
            size_t rowbase = ((size_t)n * O + oo) * L_S;
#pragma unroll
            for (int nt = 0; nt < 4; ++nt) {
                int ll = l0 + wc + nt * 16 + c;
                if (OUT_BF16)
                    ((unsigned short*)Y)[rowbase + ll] = bf16_rn(acc[mt][nt][r]);
                else
                    ((float*)Y)[rowbase + ll] = acc[mt][nt][r];
            }
        }
    }
}

// ---------------------------------------------------------------------------
// Fused dwconv + l2norm + bf16 pack for Q and K heads (unchanged).
// ---------------------------------------------------------------------------
__global__ __launch_bounds__(256) void fused_qk(const unsigned short* __restrict__ qkv_bf,
                                                const float* __restrict__ w_dw,
                                                unsigned short* __restrict__ Qb,
                                                unsigned short* __restrict__ Kb) {
    __shared__ float wsm[192];
    const int tid = threadIdx.x;
    const int l   = blockIdx.x * 256 + tid;
    const int gg  = blockIdx.y;
    const int n   = blockIdx.z;
    const int head = gg & 7;
    const int ch0  = (gg < 8) ? head * 64 : 512 + head * 64;

    if (tid < 192) wsm[tid] = w_dw[ch0 * 3 + tid];
    __syncthreads();

    const unsigned short* base = qkv_bf + ((size_t)n * C3 + ch0) * L_S;
    float y[64];
    float s = 0.f;
#pragma unroll
    for (int e = 0; e < 64; ++e) {
        const unsigned short* row = base + (size_t)e * L_S + l;
        float a = (l > 0)       ? bf16_f(row[-1]) : 0.f;
        float b = bf16_f(row[0]);
        float d = (l < L_S - 1) ? bf16_f(row[1])  : 0.f;
        float v = wsm[e * 3 + 0] * a + wsm[e * 3 + 1] * b + wsm[e * 3 + 2] * d;
        y[e] = v;
        s += v * v;
    }
    float sc = 1.0f / fmaxf(sqrtf(s), 1e-12f);

    unsigned short* dst = ((gg < 8) ? Qb : Kb) + (size_t)(n * H_N + head) * 8 * L_S * 8;
#pragma unroll
    for (int p = 0; p < 8; ++p) {
        uint4 pk = make_uint4(pk_bf16(y[8 * p + 0] * sc, y[8 * p + 1] * sc),
                              pk_bf16(y[8 * p + 2] * sc, y[8 * p + 3] * sc),
                              pk_bf16(y[8 * p + 4] * sc, y[8 * p + 5] * sc),
                              pk_bf16(y[8 * p + 6] * sc, y[8 * p + 7] * sc));
        *(uint4*)&dst[((size_t)p * L_S + l) * 8] = pk;
    }
}

// ---------------------------------------------------------------------------
// Fused dwconv + bf16 pack for V heads (unchanged).
// ---------------------------------------------------------------------------
__global__ __launch_bounds__(256) void fused_v(const unsigned short* __restrict__ qkv_bf,
                                               const float* __restrict__ w_dw,
                                               unsigned short* __restrict__ Vb) {
    const int tid = threadIdx.x;
    const int j   = tid & 63;
    const int eg  = tid >> 6;
    const int k0  = blockIdx.x * 64;
    const int h   = blockIdx.y;
    const int n   = blockIdx.z;
    const int key = k0 + j;
    const int ch0 = 1024 + h * 64 + eg * 16;

    size_t vb_base = ((size_t)(n * H_N + h) * 256 + (key >> 3)) * 512 + (key & 7);
#pragma unroll
    for (int ee = 0; ee < 16; ++ee) {
        int ch = ch0 + ee;
        const unsigned short* row = qkv_bf + ((size_t)n * C3 + ch) * L_S + key;
        float a = (key > 0)       ? bf16_f(row[-1]) : 0.f;
        float b = bf16_f(row[0]);
        float d = (key < L_S - 1) ? bf16_f(row[1])  : 0.f;
        float v = w_dw[ch * 3 + 0] * a + w_dw[ch * 3 + 1] * b + w_dw[ch * 3 + 2] * d;
        Vb[vb_base + (size_t)(eg * 16 + ee) * 8] = bf16_rn(v);
    }
}

// ---------------------------------------------------------------------------
// Flash attention v3: global_load_lds staging, double-buffered K/V,
// one barrier per chunk, Pt overlaid on Qt, pair-packed Pt writes.
// grid: (L/64, H, N), 4 waves x 16 queries.
// ---------------------------------------------------------------------------
__global__ __launch_bounds__(256) void attn3(const unsigned short* __restrict__ Qb,
                                             const unsigned short* __restrict__ Kb,
                                             const unsigned short* __restrict__ Vb,
                                             const float* __restrict__ temp,
                                             unsigned short* __restrict__ ao_hi,
                                             unsigned short* __restrict__ ao_lo) {
    __shared__ unsigned short smem[4096 + 4 * 4096];   // 40 KB
    unsigned short* Qt = smem;                         // [8][64][8]; becomes Pt
    unsigned short* Pt = smem;
    unsigned short* KV = smem + 4096;                  // K0 V0 K1 V1, 4096 u16 each
    float* Ot = (float*)(smem + 4096);                 // 16KB over K0+V0

    const int tid  = threadIdx.x;
    const int lane = tid & 63;
    const int w    = tid >> 6;
    const int g    = lane >> 4;
    const int c    = lane & 15;
    const int q0   = blockIdx.x * 64;
    const int h    = blockIdx.y;
    const int n    = blockIdx.z;

    const size_t hb = (size_t)(n * H_N + h);
    const unsigned short* Qh = Qb + hb * 8 * L_S * 8;
    const unsigned short* Kh = Kb + hb * 8 * L_S * 8;
    const unsigned short* Vh = Vb + hb * 256 * 512;
    const float t    = temp[h];
    const float negm = -fabsf(t);

    // prologue: stage Q + chunk 0 K/V (each wave stages planes w and w+4)
    gll16(Qh + ((size_t)w       * L_S + q0 + lane) * 8, &Qt[w * 512]);
    gll16(Qh + ((size_t)(w + 4) * L_S + q0 + lane) * 8, &Qt[(w + 4) * 512]);
    {
        unsigned short* Kd = KV;          // buf 0
        unsigned short* Vd = KV + 4096;
        gll16(Kh + ((size_t)w       * L_S + lane) * 8, &Kd[w * 512]);
        gll16(Kh + ((size_t)(w + 4) * L_S + lane) * 8, &Kd[(w + 4) * 512]);
        gll16(Vh + ((size_t)w       * 512 + lane * 8), &Vd[w * 512]);
        gll16(Vh + ((size_t)(w + 4) * 512 + lane * 8), &Vd[(w + 4) * 512]);
    }
    __syncthreads();

    short8 qa[2];
    qa[0] = *(short8*)&Qt[(0 + g) * 512 + (w * 16 + c) * 8];
    qa[1] = *(short8*)&Qt[(4 + g) * 512 + (w * 16 + c) * 8];
    __syncthreads();   // all qa reads done before Pt overwrites Qt

    f32x4 acc[4];
#pragma unroll
    for (int et = 0; et < 4; ++et) acc[et] = (f32x4){0.f, 0.f, 0.f, 0.f};
    float sumP[4] = {0.f, 0.f, 0.f, 0.f};

    for (int tchunk = 0; tchunk < 32; ++tchunk) {
        const int cur = tchunk & 1;
        if (tchunk < 31) {          // prefetch next chunk into other buffer
            const int k1 = (tchunk + 1) * 64;
            unsigned short* Kd = KV + (cur ^ 1) * 8192;
            unsigned short* Vd = KV + (cur ^ 1) * 8192 + 4096;
            gll16(Kh + ((size_t)w * L_S + k1 + lane) * 8,       &Kd[w * 512]);
            gll16(Kh + ((size_t)(w + 4) * L_S + k1 + lane) * 8, &Kd[(w + 4) * 512]);
            gll16(Vh + ((size_t)(k1 / 8 + w)     * 512 + lane * 8), &Vd[w * 512]);
            gll16(Vh + ((size_t)(k1 / 8 + w + 4) * 512 + lane * 8), &Vd[(w + 4) * 512]);
        }

        const unsigned short* Kc_ = KV + cur * 8192;
        const unsigned short* Vc_ = KV + cur * 8192 + 4096;

        // S = Q K^T
        f32x4 sf[4];
#pragma unroll
        for (int kt = 0; kt < 4; ++kt) sf[kt] = (f32x4){0.f, 0.f, 0.f, 0.f};
#pragma unroll
        for (int s = 0; s < 2; ++s) {
#pragma unroll
            for (int kt = 0; kt < 4; ++kt) {
                short8 kb = *(short8*)&Kc_[(4 * s + g) * 512 + (kt * 16 + c) * 8];
                sf[kt] = __builtin_amdgcn_mfma_f32_16x16x32_bf16(qa[s], kb, sf[kt], 0, 0, 0);
            }
        }

        // fixed-max softmax: p = exp(s*t - |t|); pair-pack Pt writes
#pragma unroll
        for (int r = 0; r < 4; ++r) {
            float p0 = __expf(fmaf(sf[0][r], t, negm));
            float p1 = __expf(fmaf(sf[1][r], t, negm));
            float p2 = __expf(fmaf(sf[2][r], t, negm));
            float p3 = __expf(fmaf(sf[3][r], t, negm));
            sumP[r] += (p0 + p1) + (p2 + p3);
            float x0 = __shfl_xor(p0, 1);
            float x1 = __shfl_xor(p1, 1);
            float x2 = __shfl_xor(p2, 1);
            float x3 = __shfl_xor(p3, 1);
            if (!(c & 1)) {
                int q = w * 16 + g * 4 + r;
                int base = q * 8 + (c & 7);
                *(unsigned int*)&Pt[(0 + (c >> 3)) * 512 + base] = pk_bf16(p0, x0);
                *(unsigned int*)&Pt[(2 + (c >> 3)) * 512 + base] = pk_bf16(p1, x1);
                *(unsigned int*)&Pt[(4 + (c >> 3)) * 512 + base] = pk_bf16(p2, x2);
                *(unsigned int*)&Pt[(6 + (c >> 3)) * 512 + base] = pk_bf16(p3, x3);
            }
        }

        // O += P V  (Pt traffic is wave-local)
#pragma unroll
        for (int s = 0; s < 2; ++s) {
            short8 pa = *(short8*)&Pt[(4 * s + g) * 512 + (w * 16 + c) * 8];
#pragma unroll
            for (int et = 0; et < 4; ++et) {
                short8 vb = *(short8*)&Vc_[(4 * s + g) * 512 + (et * 16 + c) * 8];
                acc[et] = __builtin_amdgcn_mfma_f32_16x16x32_bf16(pa, vb, acc[et], 0, 0, 0);
            }
        }

        __syncthreads();   // drains prefetch vmcnt + separates buffers
    }

    // final denominator reduce
    float inv[4];
#pragma unroll
    for (int r = 0; r < 4; ++r) {
        float ps = sumP[r];
        ps += __shfl_xor(ps, 1);
        ps += __shfl_xor(ps, 2);
        ps += __shfl_xor(ps, 4);
        ps += __shfl_xor(ps, 8);
        inv[r] = 1.0f / ps;
    }

    // Ot overlays K0/V0 (all compute done after final loop barrier)
#pragma unroll
    for (int et = 0; et < 4; ++et) {
        int e = et * 16 + c;
#pragma unroll
        for (int r = 0; r < 4; ++r) {
            int q = w * 16 + g * 4 + r;
            Ot[q * 64 + (e ^ (q & 31))] = acc[et][r] * inv[r];
        }
    }
    __syncthreads();

    for (int tt = tid; tt < 4096; tt += 256) {
        int e = tt >> 6, qq = tt & 63;
        float v = Ot[qq * 64 + (e ^ (qq & 31))];
        unsigned short hi_ = bf16_rn(v);
        unsigned short lo_ = bf16_rn(v - bf16_f(hi_));
        size_t off = ((size_t)n * D_F + h * 64 + e) * L_S + q0 + qq;
        ao_hi[off] = hi_;
        ao_lo[off] = lo_;
    }
}

// ---------------------------------------------------------------------------
extern "C" void kernel_launch(void* const* d_in, const int* in_sizes, int n_in,
                              void* d_out, int out_size, void* d_ws, size_t ws_size,
                              hipStream_t stream) {
    const float* x      = (const float*)d_in[0];   // (4, 512, 2048)
    const float* w_qkv  = (const float*)d_in[1];   // (1536, 512)
    const float* w_dw   = (const float*)d_in[2];   // (1536, 3)
    const float* w_proj = (const float*)d_in[3];   // (512, 512)
    const float* temp   = (const float*)d_in[4];   // (8)
    float* out = (float*)d_out;

    const size_t XE  = (size_t)N_B * D_F * L_S;    // 4,194,304
    const size_t WQE = (size_t)C3 * D_F;           // 786,432
    const size_t WPE = (size_t)D_F * D_F;          // 262,144

    char* ws = (char*)d_ws;
    unsigned short* qkv_bf = (unsigned short*)ws;               // 25,165,824 B
    unsigned short* Qb     = (unsigned short*)(ws + 25165824);  //  8,388,608 B
    unsigned short* Kb     = (unsigned short*)(ws + 33554432);  //  8,388,608 B
    unsigned short* Vb     = (unsigned short*)(ws + 41943040);  //  8,388,608 B
    unsigned short* x_hi   = (unsigned short*)(ws + 50331648);  //  8,388,608 B
    unsigned short* x_lo   = (unsigned short*)(ws + 58720256);  //  8,388,608 B
    unsigned short* wq_hi  = (unsigned short*)(ws + 67108864);  //  1,572,864 B
    unsigned short* wq_lo  = wq_hi + WQE;
    unsigned short* wp_hi  = (unsigned short*)(ws + 70254592);  //    524,288 B
    unsigned short* wp_lo  = wp_hi + WPE;                       // ends ~71.3 MB
    unsigned short* ao_hi  = x_hi;   // reuse (x consumed by QKV gemm)
    unsigned short* ao_lo  = x_lo;

    // 0) precision splits
    cvt_split<<<dim3((XE / 4 + 255) / 256), 256, 0, stream>>>(x, x_hi, x_lo, XE / 4);
    cvt_split<<<dim3((WQE / 4 + 255) / 256), 256, 0, stream>>>(w_qkv, wq_hi, wq_lo, WQE / 4);
    cvt_split<<<dim3((WPE / 4 + 255) / 256), 256, 0, stream>>>(w_proj, wp_hi, wp_lo, WPE / 4);

    // 1) QKV 1x1 conv: plain bf16 MFMA -> bf16
    gemm_mfma<0, 1><<<dim3(L_S / 128, C3 / 128, N_B), 256, 0, stream>>>(
        wq_hi, nullptr, x_hi, nullptr, qkv_bf, C3, D_F);

    // 2) fused dwconv (+l2norm) + MFMA-layout bf16 pack
    fused_qk<<<dim3(L_S / 256, 16, N_B), 256, 0, stream>>>(qkv_bf, w_dw, Qb, Kb);
    fused_v<<<dim3(L_S / 64, H_N, N_B), 256, 0, stream>>>(qkv_bf, w_dw, Vb);

    // 3) attention -> split bf16 hi/lo directly
    attn3<<<dim3(L_S / 64, H_N, N_B), 256, 0, stream>>>(Qb, Kb, Vb, temp, ao_hi, ao_lo);

    // 4) 3-term split-bf16 proj GEMM -> fp32 out
    gemm_mfma<1, 0><<<dim3(L_S / 128, D_F / 128, N_B), 256, 0, stream>>>(
        wp_hi, wp_lo, ao_hi, ao_lo, out, D_F, D_F);
}

// Round 6
// 251.632 us; speedup vs baseline: 1.0298x; 1.0298x over previous
//
#include <hip/hip_runtime.h>
#include <hip/hip_bf16.h>
#include <cstdint>
#include <cstddef>

#define N_B 4
#define D_F 512
#define L_S 2048
#define H_N 8
#define DH  64
#define C3  (3*D_F)   // 1536

typedef __attribute__((ext_vector_type(8)))  short short8;
typedef __attribute__((ext_vector_type(4)))  float f32x4;
typedef __attribute__((ext_vector_type(16))) float f32x16;

__device__ __forceinline__ unsigned int pk_bf16(float a, float b) {
    __hip_bfloat162 h = __float22bfloat162_rn(float2{a, b});
    union { __hip_bfloat162 h; unsigned int u; } cv;
    cv.h = h;
    return cv.u;
}
__device__ __forceinline__ unsigned short bf16_rn(float f) {
    union { float f; unsigned int u; } c; c.f = f;
    unsigned int r = c.u + 0x7FFF + ((c.u >> 16) & 1);
    return (unsigned short)(r >> 16);
}
__device__ __forceinline__ float bf16_f(unsigned short h) {
    union { unsigned int u; float f; } c; c.u = ((unsigned int)h) << 16;
    return c.f;
}

// async global->LDS, 16B per lane; lds base must be wave-uniform.
__device__ __forceinline__ void gll16(const unsigned short* g, unsigned short* l) {
    __builtin_amdgcn_global_load_lds(
        (const __attribute__((address_space(1))) unsigned int*)g,
        (__attribute__((address_space(3))) unsigned int*)l,
        16, 0, 0);
}

// ---------------------------------------------------------------------------
// Split fp32 -> bf16 hi + bf16 lo
// ---------------------------------------------------------------------------
__global__ __launch_bounds__(256) void cvt_split(const float* __restrict__ src,
                                                 unsigned short* __restrict__ hi,
                                                 unsigned short* __restrict__ lo,
                                                 int n4) {
    int i = blockIdx.x * 256 + threadIdx.x;
    if (i >= n4) return;
    float4 v = ((const float4*)src)[i];
    ushort4 h, l;
    h.x = bf16_rn(v.x); l.x = bf16_rn(v.x - bf16_f(h.x));
    h.y = bf16_rn(v.y); l.y = bf16_rn(v.y - bf16_f(h.y));
    h.z = bf16_rn(v.z); l.z = bf16_rn(v.z - bf16_f(h.z));
    h.w = bf16_rn(v.w); l.w = bf16_rn(v.w - bf16_f(h.w));
    ((ushort4*)hi)[i] = h;
    ((ushort4*)lo)[i] = l;
}

// ---------------------------------------------------------------------------
// MFMA GEMM (unchanged): Y[n][o][l] = sum_c W[o][c] * X[n][c][l]
// ---------------------------------------------------------------------------
template<int SPLIT, int OUT_BF16>
__global__ __launch_bounds__(256) void gemm_mfma(const unsigned short* __restrict__ Whi,
                                                 const unsigned short* __restrict__ Wlo,
                                                 const unsigned short* __restrict__ Xhi,
                                                 const unsigned short* __restrict__ Xlo,
                                                 void* __restrict__ Y,
                                                 int O, int C) {
    __shared__ unsigned short Wt[SPLIT ? 2 : 1][4][128 * 8];
    __shared__ unsigned short Xt[SPLIT ? 2 : 1][4][128 * 8];

    const int tid  = threadIdx.x;
    const int lane = tid & 63;
    const int w    = tid >> 6;
    const int g    = lane >> 4;
    const int c    = lane & 15;
    const int wr   = (w >> 1) * 64;
    const int wc   = (w & 1) * 64;
    const int l0   = blockIdx.x * 128;
    const int o0   = blockIdx.y * 128;
    const int n    = blockIdx.z;

    const unsigned short* Xn_hi = Xhi + (size_t)n * C * L_S;
    const unsigned short* Xn_lo = SPLIT ? (Xlo + (size_t)n * C * L_S) : nullptr;

    f32x4 acc[4][4];
#pragma unroll
    for (int mt = 0; mt < 4; ++mt)
#pragma unroll
        for (int nt = 0; nt < 4; ++nt) acc[mt][nt] = (f32x4){0.f, 0.f, 0.f, 0.f};

    for (int c0 = 0; c0 < C; c0 += 32) {
        __syncthreads();
#pragma unroll
        for (int t = tid; t < 512; t += 256) {
            int o = t & 127, cp = t >> 7;
            size_t off = (size_t)(o0 + o) * C + c0 + cp * 8;
            *(uint4*)&Wt[0][cp][o * 8] = *(const uint4*)(Whi + off);
            if (SPLIT) *(uint4*)&Wt[1][cp][o * 8] = *(const uint4*)(Wlo + off);
        }
#pragma unroll
        for (int t = tid; t < 512; t += 256) {
            int l = t & 127, cp = t >> 7;
            const unsigned short* src = Xn_hi + (size_t)(c0 + cp * 8) * L_S + l0 + l;
            short8 v;
#pragma unroll
            for (int i = 0; i < 8; ++i) v[i] = (short)src[(size_t)i * L_S];
            *(short8*)&Xt[0][cp][l * 8] = v;
            if (SPLIT) {
                const unsigned short* srcl = Xn_lo + (size_t)(c0 + cp * 8) * L_S + l0 + l;
                short8 vl;
#pragma unroll
                for (int i = 0; i < 8; ++i) vl[i] = (short)srcl[(size_t)i * L_S];
                *(short8*)&Xt[1][cp][l * 8] = vl;
            }
        }
        __syncthreads();

        short8 a0[4], b0[4];
#pragma unroll
        for (int mt = 0; mt < 4; ++mt) a0[mt] = *(short8*)&Wt[0][g][(wr + mt * 16 + c) * 8];
#pragma unroll
        for (int nt = 0; nt < 4; ++nt) b0[nt] = *(short8*)&Xt[0][g][(wc + nt * 16 + c) * 8];

        if (SPLIT) {
            short8 a1[4], b1[4];
#pragma unroll
            for (int mt = 0; mt < 4; ++mt) a1[mt] = *(short8*)&Wt[1][g][(wr + mt * 16 + c) * 8];
#pragma unroll
            for (int nt = 0; nt < 4; ++nt) b1[nt] = *(short8*)&Xt[1][g][(wc + nt * 16 + c) * 8];
#pragma unroll
            for (int mt = 0; mt < 4; ++mt)
#pragma unroll
                for (int nt = 0; nt < 4; ++nt) {
                    acc[mt][nt] = __builtin_amdgcn_mfma_f32_16x16x32_bf16(a0[mt], b0[nt], acc[mt][nt], 0, 0, 0);
                    acc[mt][nt] = __builtin_amdgcn_mfma_f32_16x16x32_bf16(a0[mt], b1[nt], acc[mt][nt], 0, 0, 0);
                    acc[mt][nt] = __builtin_amdgcn_mfma_f32_16x16x32_bf16(a1[mt], b0[nt], acc[mt][nt], 0, 0, 0);
                }
        } else {
#pragma unroll
            for (int mt = 0; mt < 4; ++mt)
#pragma unroll
                for (int nt = 0; nt < 4; ++nt)
                    acc[mt][nt] = __builtin_amdgcn_mfma_f32_16x16x32_bf16(a0[mt], b0[nt], acc[mt][nt], 0, 0, 0);
        }
    }

#pragma unroll
    for (int mt = 0; mt < 4; ++mt) {
#pragma unroll
        for (int r = 0; r < 4; ++r) {
            int oo = o0 + wr + mt * 16 + g * 4 + r;
            size_t rowbase = ((size_t)n * O + oo) * L_S;
#pragma unroll
            for (int nt = 0; nt < 4; ++nt) {
                int ll = l0 + wc + nt * 16 + c;
                if (OUT_BF16)
                    ((unsigned short*)Y)[rowbase + ll] = bf16_rn(acc[mt][nt][r]);
                else
                    ((float*)Y)[rowbase + ll] = acc[mt][nt][r];
            }
        }
    }
}

// ---------------------------------------------------------------------------
// Fused dwconv + l2norm + bf16 pack for Q and K heads (unchanged).
// ---------------------------------------------------------------------------
__global__ __launch_bounds__(256) void fused_qk(const unsigned short* __restrict__ qkv_bf,
                                                const float* __restrict__ w_dw,
                                                unsigned short* __restrict__ Qb,
                                                unsigned short* __restrict__ Kb) {
    __shared__ float wsm[192];
    const int tid = threadIdx.x;
    const int l   = blockIdx.x * 256 + tid;
    const int gg  = blockIdx.y;
    const int n   = blockIdx.z;
    const int head = gg & 7;
    const int ch0  = (gg < 8) ? head * 64 : 512 + head * 64;

    if (tid < 192) wsm[tid] = w_dw[ch0 * 3 + tid];
    __syncthreads();

    const unsigned short* base = qkv_bf + ((size_t)n * C3 + ch0) * L_S;
    float y[64];
    float s = 0.f;
#pragma unroll
    for (int e = 0; e < 64; ++e) {
        const unsigned short* row = base + (size_t)e * L_S + l;
        float a = (l > 0)       ? bf16_f(row[-1]) : 0.f;
        float b = bf16_f(row[0]);
        float d = (l < L_S - 1) ? bf16_f(row[1])  : 0.f;
        float v = wsm[e * 3 + 0] * a + wsm[e * 3 + 1] * b + wsm[e * 3 + 2] * d;
        y[e] = v;
        s += v * v;
    }
    float sc = 1.0f / fmaxf(sqrtf(s), 1e-12f);

    unsigned short* dst = ((gg < 8) ? Qb : Kb) + (size_t)(n * H_N + head) * 8 * L_S * 8;
#pragma unroll
    for (int p = 0; p < 8; ++p) {
        uint4 pk = make_uint4(pk_bf16(y[8 * p + 0] * sc, y[8 * p + 1] * sc),
                              pk_bf16(y[8 * p + 2] * sc, y[8 * p + 3] * sc),
                              pk_bf16(y[8 * p + 4] * sc, y[8 * p + 5] * sc),
                              pk_bf16(y[8 * p + 6] * sc, y[8 * p + 7] * sc));
        *(uint4*)&dst[((size_t)p * L_S + l) * 8] = pk;
    }
}

// ---------------------------------------------------------------------------
// Fused dwconv + bf16 pack for V heads (unchanged).
// ---------------------------------------------------------------------------
__global__ __launch_bounds__(256) void fused_v(const unsigned short* __restrict__ qkv_bf,
                                               const float* __restrict__ w_dw,
                                               unsigned short* __restrict__ Vb) {
    const int tid = threadIdx.x;
    const int j   = tid & 63;
    const int eg  = tid >> 6;
    const int k0  = blockIdx.x * 64;
    const int h   = blockIdx.y;
    const int n   = blockIdx.z;
    const int key = k0 + j;
    const int ch0 = 1024 + h * 64 + eg * 16;

    size_t vb_base = ((size_t)(n * H_N + h) * 256 + (key >> 3)) * 512 + (key & 7);
#pragma unroll
    for (int ee = 0; ee < 16; ++ee) {
        int ch = ch0 + ee;
        const unsigned short* row = qkv_bf + ((size_t)n * C3 + ch) * L_S + key;
        float a = (key > 0)       ? bf16_f(row[-1]) : 0.f;
        float b = bf16_f(row[0]);
        float d = (key < L_S - 1) ? bf16_f(row[1])  : 0.f;
        float v = w_dw[ch * 3 + 0] * a + w_dw[ch * 3 + 1] * b + w_dw[ch * 3 + 2] * d;
        Vb[vb_base + (size_t)(eg * 16 + ee) * 8] = bf16_rn(v);
    }
}

// ---------------------------------------------------------------------------
// Flash attention v4: 32x32x16 MFMA, 32 q per wave, swapped QK^T so softmax
// is lane-local (no shfl, no rescale), exp2-direct, gll16 dbuf staging.
// C/D layout (m74/m101-verified): col=lane&31, row=(reg&3)+8*(reg>>2)+4*(lane>>5)
// A/B frag: row|col = lane&31, k = (lane>>5)*8 + j
// grid: (L/128, H, N), 4 waves x 32 queries.
// ---------------------------------------------------------------------------
__global__ __launch_bounds__(256) void attn4(const unsigned short* __restrict__ Qb,
                                             const unsigned short* __restrict__ Kb,
                                             const unsigned short* __restrict__ Vb,
                                             const float* __restrict__ temp,
                                             unsigned short* __restrict__ ao_hi,
                                             unsigned short* __restrict__ ao_lo) {
    __shared__ unsigned short KV[16384];      // 32KB: buf0{K,V} buf1{K,V}; Q-stage & Ot overlay
    __shared__ unsigned short PtAll[4 * 2048];// 16KB: per-wave P [8 planes][32 q][8 keys]
    __shared__ float sm[128];                 // per-q inverse denominators
    float* Ot = (float*)KV;                   // 128q x 64e f32 (32KB) after final barrier

    const int tid  = threadIdx.x;
    const int lane = tid & 63;
    const int w    = tid >> 6;
    const int c32  = lane & 31;
    const int h    = lane >> 5;
    const int q0   = blockIdx.x * 128;
    const int hd   = blockIdx.y;
    const int n    = blockIdx.z;

    const size_t hb = (size_t)(n * H_N + hd);
    const unsigned short* Qh = Qb + hb * 8 * L_S * 8;
    const unsigned short* Kh = Kb + hb * 8 * L_S * 8;
    const unsigned short* Vh = Vb + hb * 256 * 512;
    const float t     = temp[hd];
    const float t2    = t * 1.44269504088896f;
    const float negm2 = -fabsf(t2);
    unsigned short* Pt = PtAll + w * 2048;

    // ---- prologue: Q planes into buf1 area; chunk 0 K/V into buf0
    unsigned short* Qs = KV + 8192;
    gll16(Qh + ((size_t)w * L_S + q0 + lane) * 8,            Qs + w * 1024);
    gll16(Qh + ((size_t)w * L_S + q0 + 64 + lane) * 8,       Qs + w * 1024 + 512);
    gll16(Qh + ((size_t)(w + 4) * L_S + q0 + lane) * 8,      Qs + (w + 4) * 1024);
    gll16(Qh + ((size_t)(w + 4) * L_S + q0 + 64 + lane) * 8, Qs + (w + 4) * 1024 + 512);
    gll16(Kh + ((size_t)w * L_S + lane) * 8,       KV + w * 512);
    gll16(Kh + ((size_t)(w + 4) * L_S + lane) * 8, KV + (w + 4) * 512);
    gll16(Vh + ((size_t)w * 512 + lane * 8),       KV + 4096 + w * 512);
    gll16(Vh + ((size_t)(w + 4) * 512 + lane * 8), KV + 4096 + (w + 4) * 512);
    __syncthreads();

    short8 qa[4];
#pragma unroll
    for (int es = 0; es < 4; ++es)
        qa[es] = *(short8*)&Qs[(es * 2 + h) * 1024 + (w * 32 + c32) * 8];
    __syncthreads();   // qa reads done before chunk-1 prefetch overwrites Qs

    f32x16 acc0, acc1;
#pragma unroll
    for (int i = 0; i < 16; ++i) { acc0[i] = 0.f; acc1[i] = 0.f; }
    float sumP = 0.f;

#define SOFTMAX_TILE(SF, KT)                                                   \
    _Pragma("unroll")                                                          \
    for (int G = 0; G < 4; ++G) {                                              \
        float p0 = exp2f(fmaf((SF)[4 * G + 0], t2, negm2));                    \
        float p1 = exp2f(fmaf((SF)[4 * G + 1], t2, negm2));                    \
        float p2 = exp2f(fmaf((SF)[4 * G + 2], t2, negm2));                    \
        float p3 = exp2f(fmaf((SF)[4 * G + 3], t2, negm2));                    \
        sumP += (p0 + p1) + (p2 + p3);                                         \
        unsigned long long pr = ((unsigned long long)pk_bf16(p2, p3) << 32)    \
                              | (unsigned long long)pk_bf16(p0, p1);           \
        *(unsigned long long*)&Pt[((KT) * 4 + G) * 256 + c32 * 8 + h * 4] = pr;\
    }

    for (int tc = 0; tc < 32; ++tc) {
        const int cur = tc & 1;
        const unsigned short* Kc = KV + cur * 8192;
        const unsigned short* Vc = KV + cur * 8192 + 4096;

        if (tc < 31) {   // prefetch next chunk into other buffer
            const int k1 = (tc + 1) * 64;
            unsigned short* Kd = KV + (cur ^ 1) * 8192;
            unsigned short* Vd = Kd + 4096;
            gll16(Kh + ((size_t)w * L_S + k1 + lane) * 8,           Kd + w * 512);
            gll16(Kh + ((size_t)(w + 4) * L_S + k1 + lane) * 8,     Kd + (w + 4) * 512);
            gll16(Vh + ((size_t)(k1 / 8 + w) * 512 + lane * 8),     Vd + w * 512);
            gll16(Vh + ((size_t)(k1 / 8 + w + 4) * 512 + lane * 8), Vd + (w + 4) * 512);
        }

        // ---- S^T = K Q^T : sf[kt] lane holds 16 keys for q = w*32 + c32
        f32x16 sf0, sf1;
#pragma unroll
        for (int i = 0; i < 16; ++i) { sf0[i] = 0.f; sf1[i] = 0.f; }
#pragma unroll
        for (int es = 0; es < 4; ++es) {
            short8 ka0 = *(short8*)&Kc[(es * 2 + h) * 512 + c32 * 8];
            short8 ka1 = *(short8*)&Kc[(es * 2 + h) * 512 + (32 + c32) * 8];
            sf0 = __builtin_amdgcn_mfma_f32_32x32x16_bf16(ka0, qa[es], sf0, 0, 0, 0);
            sf1 = __builtin_amdgcn_mfma_f32_32x32x16_bf16(ka1, qa[es], sf1, 0, 0, 0);
        }

        // ---- softmax: p = exp2(s*t2 - |t2|), lane-local pairs -> Pt
        SOFTMAX_TILE(sf0, 0)
        SOFTMAX_TILE(sf1, 1)

        // ---- O += P V
#pragma unroll
        for (int ks = 0; ks < 4; ++ks) {
            short8 pa  = *(short8*)&Pt[(ks * 2 + h) * 256 + c32 * 8];
            short8 vb0 = *(short8*)&Vc[(ks * 2 + h) * 512 + c32 * 8];
            short8 vb1 = *(short8*)&Vc[(ks * 2 + h) * 512 + (32 + c32) * 8];
            acc0 = __builtin_amdgcn_mfma_f32_32x32x16_bf16(pa, vb0, acc0, 0, 0, 0);
            acc1 = __builtin_amdgcn_mfma_f32_32x32x16_bf16(pa, vb1, acc1, 0, 0, 0);
        }

        __syncthreads();   // drains prefetch + protects buffer swap
    }
#undef SOFTMAX_TILE

    // ---- final denominator: other half of keys is in lane^32
    sumP += __shfl_xor(sumP, 32);
    sm[w * 32 + c32] = 1.0f / sumP;   // both halves write same value (benign)

    float inv[16];
#pragma unroll
    for (int r = 0; r < 16; ++r) {
        int ql = (r & 3) + 8 * (r >> 2) + 4 * h;
        inv[r] = sm[w * 32 + ql];
    }

    // ---- Ot overlay (KV free after final barrier), swizzled for both sides
#pragma unroll
    for (int r = 0; r < 16; ++r) {
        int ql = (r & 3) + 8 * (r >> 2) + 4 * h;
        int qg = w * 32 + ql;
        Ot[qg * 64 + (c32 ^ (qg & 31))]        = acc0[r] * inv[r];
        Ot[qg * 64 + ((32 + c32) ^ (qg & 31))] = acc1[r] * inv[r];
    }
    __syncthreads();

    for (int tt = tid; tt < 8192; tt += 256) {
        int e = tt >> 7, qq = tt & 127;
        float v = Ot[qq * 64 + (e ^ (qq & 31))];
        unsigned short hi_ = bf16_rn(v);
        unsigned short lo_ = bf16_rn(v - bf16_f(hi_));
        size_t off = ((size_t)n * D_F + hd * 64 + e) * L_S + q0 + qq;
        ao_hi[off] = hi_;
        ao_lo[off] = lo_;
    }
}

// ---------------------------------------------------------------------------
extern "C" void kernel_launch(void* const* d_in, const int* in_sizes, int n_in,
                              void* d_out, int out_size, void* d_ws, size_t ws_size,
                              hipStream_t stream) {
    const float* x      = (const float*)d_in[0];   // (4, 512, 2048)
    const float* w_qkv  = (const float*)d_in[1];   // (1536, 512)
    const float* w_dw   = (const float*)d_in[2];   // (1536, 3)
    const float* w_proj = (const float*)d_in[3];   // (512, 512)
    const float* temp   = (const float*)d_in[4];   // (8)
    float* out = (float*)d_out;

    const size_t XE  = (size_t)N_B * D_F * L_S;    // 4,194,304
    const size_t WQE = (size_t)C3 * D_F;           // 786,432
    const size_t WPE = (size_t)D_F * D_F;          // 262,144

    char* ws = (char*)d_ws;
    unsigned short* qkv_bf = (unsigned short*)ws;               // 25,165,824 B
    unsigned short* Qb     = (unsigned short*)(ws + 25165824);  //  8,388,608 B
    unsigned short* Kb     = (unsigned short*)(ws + 33554432);  //  8,388,608 B
    unsigned short* Vb     = (unsigned short*)(ws + 41943040);  //  8,388,608 B
    unsigned short* x_hi   = (unsigned short*)(ws + 50331648);  //  8,388,608 B
    unsigned short* x_lo   = (unsigned short*)(ws + 58720256);  //  8,388,608 B
    unsigned short* wq_hi  = (unsigned short*)(ws + 67108864);  //  1,572,864 B
    unsigned short* wq_lo  = wq_hi + WQE;
    unsigned short* wp_hi  = (unsigned short*)(ws + 70254592);  //    524,288 B
    unsigned short* wp_lo  = wp_hi + WPE;                       // ends ~71.3 MB
    unsigned short* ao_hi  = x_hi;   // reuse (x consumed by QKV gemm)
    unsigned short* ao_lo  = x_lo;

    // 0) precision splits
    cvt_split<<<dim3((XE / 4 + 255) / 256), 256, 0, stream>>>(x, x_hi, x_lo, XE / 4);
    cvt_split<<<dim3((WQE / 4 + 255) / 256), 256, 0, stream>>>(w_qkv, wq_hi, wq_lo, WQE / 4);
    cvt_split<<<dim3((WPE / 4 + 255) / 256), 256, 0, stream>>>(w_proj, wp_hi, wp_lo, WPE / 4);

    // 1) QKV 1x1 conv: plain bf16 MFMA -> bf16
    gemm_mfma<0, 1><<<dim3(L_S / 128, C3 / 128, N_B), 256, 0, stream>>>(
        wq_hi, nullptr, x_hi, nullptr, qkv_bf, C3, D_F);

    // 2) fused dwconv (+l2norm) + MFMA-layout bf16 pack
    fused_qk<<<dim3(L_S / 256, 16, N_B), 256, 0, stream>>>(qkv_bf, w_dw, Qb, Kb);
    fused_v<<<dim3(L_S / 64, H_N, N_B), 256, 0, stream>>>(qkv_bf, w_dw, Vb);

    // 3) attention (32x32 MFMA, swapped QK^T) -> split bf16 hi/lo
    attn4<<<dim3(L_S / 128, H_N, N_B), 256, 0, stream>>>(Qb, Kb, Vb, temp, ao_hi, ao_lo);

    // 4) 3-term split-bf16 proj GEMM -> fp32 out
    gemm_mfma<1, 0><<<dim3(L_S / 128, D_F / 128, N_B), 256, 0, stream>>>(
        wp_hi, wp_lo, ao_hi, ao_lo, out, D_F, D_F);
}

// Round 7
// 179.577 us; speedup vs baseline: 1.4430x; 1.4013x over previous
//
#include <hip/hip_runtime.h>
#include <hip/hip_bf16.h>
#include <cstdint>
#include <cstddef>

#define N_B 4
#define D_F 512
#define L_S 2048
#define H_N 8
#define DH  64
#define C3  (3*D_F)   // 1536

typedef __attribute__((ext_vector_type(8)))  short short8;
typedef __attribute__((ext_vector_type(4)))  float f32x4;
typedef __attribute__((ext_vector_type(16))) float f32x16;

__device__ __forceinline__ unsigned int pk_bf16(float a, float b) {
    __hip_bfloat162 h = __float22bfloat162_rn(float2{a, b});
    union { __hip_bfloat162 h; unsigned int u; } cv;
    cv.h = h;
    return cv.u;
}
__device__ __forceinline__ unsigned short bf16_rn(float f) {
    union { float f; unsigned int u; } c; c.f = f;
    unsigned int r = c.u + 0x7FFF + ((c.u >> 16) & 1);
    return (unsigned short)(r >> 16);
}
__device__ __forceinline__ float bf16_f(unsigned short h) {
    union { unsigned int u; float f; } c; c.u = ((unsigned int)h) << 16;
    return c.f;
}

// async global->LDS, 16B per lane; lds base must be wave-uniform.
__device__ __forceinline__ void gll16(const unsigned short* g, unsigned short* l) {
    __builtin_amdgcn_global_load_lds(
        (const __attribute__((address_space(1))) unsigned int*)g,
        (__attribute__((address_space(3))) unsigned int*)l,
        16, 0, 0);
}

// ---------------------------------------------------------------------------
// Split fp32 -> bf16 hi + bf16 lo
// ---------------------------------------------------------------------------
__global__ __launch_bounds__(256) void cvt_split(const float* __restrict__ src,
                                                 unsigned short* __restrict__ hi,
                                                 unsigned short* __restrict__ lo,
                                                 int n4) {
    int i = blockIdx.x * 256 + threadIdx.x;
    if (i >= n4) return;
    float4 v = ((const float4*)src)[i];
    ushort4 h, l;
    h.x = bf16_rn(v.x); l.x = bf16_rn(v.x - bf16_f(h.x));
    h.y = bf16_rn(v.y); l.y = bf16_rn(v.y - bf16_f(h.y));
    h.z = bf16_rn(v.z); l.z = bf16_rn(v.z - bf16_f(h.z));
    h.w = bf16_rn(v.w); l.w = bf16_rn(v.w - bf16_f(h.w));
    ((ushort4*)hi)[i] = h;
    ((ushort4*)lo)[i] = l;
}

// ---------------------------------------------------------------------------
// MFMA GEMM (unchanged): Y[n][o][l] = sum_c W[o][c] * X[n][c][l]
// ---------------------------------------------------------------------------
template<int SPLIT, int OUT_BF16>
__global__ __launch_bounds__(256) void gemm_mfma(const unsigned short* __restrict__ Whi,
                                                 const unsigned short* __restrict__ Wlo,
                                                 const unsigned short* __restrict__ Xhi,
                                                 const unsigned short* __restrict__ Xlo,
                                                 void* __restrict__ Y,
                                                 int O, int C) {
    __shared__ unsigned short Wt[SPLIT ? 2 : 1][4][128 * 8];
    __shared__ unsigned short Xt[SPLIT ? 2 : 1][4][128 * 8];

    const int tid  = threadIdx.x;
    const int lane = tid & 63;
    const int w    = tid >> 6;
    const int g    = lane >> 4;
    const int c    = lane & 15;
    const int wr   = (w >> 1) * 64;
    const int wc   = (w & 1) * 64;
    const int l0   = blockIdx.x * 128;
    const int o0   = blockIdx.y * 128;
    const int n    = blockIdx.z;

    const unsigned short* Xn_hi = Xhi + (size_t)n * C * L_S;
    const unsigned short* Xn_lo = SPLIT ? (Xlo + (size_t)n * C * L_S) : nullptr;

    f32x4 acc[4][4];
#pragma unroll
    for (int mt = 0; mt < 4; ++mt)
#pragma unroll
        for (int nt = 0; nt < 4; ++nt) acc[mt][nt] = (f32x4){0.f, 0.f, 0.f, 0.f};

    for (int c0 = 0; c0 < C; c0 += 32) {
        __syncthreads();
#pragma unroll
        for (int t = tid; t < 512; t += 256) {
            int o = t & 127, cp = t >> 7;
            size_t off = (size_t)(o0 + o) * C + c0 + cp * 8;
            *(uint4*)&Wt[0][cp][o * 8] = *(const uint4*)(Whi + off);
            if (SPLIT) *(uint4*)&Wt[1][cp][o * 8] = *(const uint4*)(Wlo + off);
        }
#pragma unroll
        for (int t = tid; t < 512; t += 256) {
            int l = t & 127, cp = t >> 7;
            const unsigned short* src = Xn_hi + (size_t)(c0 + cp * 8) * L_S + l0 + l;
            short8 v;
#pragma unroll
            for (int i = 0; i < 8; ++i) v[i] = (short)src[(size_t)i * L_S];
            *(short8*)&Xt[0][cp][l * 8] = v;
            if (SPLIT) {
                const unsigned short* srcl = Xn_lo + (size_t)(c0 + cp * 8) * L_S + l0 + l;
                short8 vl;
#pragma unroll
                for (int i = 0; i < 8; ++i) vl[i] = (short)srcl[(size_t)i * L_S];
                *(short8*)&Xt[1][cp][l * 8] = vl;
            }
        }
        __syncthreads();

        short8 a0[4], b0[4];
#pragma unroll
        for (int mt = 0; mt < 4; ++mt) a0[mt] = *(short8*)&Wt[0][g][(wr + mt * 16 + c) * 8];
#pragma unroll
        for (int nt = 0; nt < 4; ++nt) b0[nt] = *(short8*)&Xt[0][g][(wc + nt * 16 + c) * 8];

        if (SPLIT) {
            short8 a1[4], b1[4];
#pragma unroll
            for (int mt = 0; mt < 4; ++mt) a1[mt] = *(short8*)&Wt[1][g][(wr + mt * 16 + c) * 8];
#pragma unroll
            for (int nt = 0; nt < 4; ++nt) b1[nt] = *(short8*)&Xt[1][g][(wc + nt * 16 + c) * 8];
#pragma unroll
            for (int mt = 0; mt < 4; ++mt)
#pragma unroll
                for (int nt = 0; nt < 4; ++nt) {
                    acc[mt][nt] = __builtin_amdgcn_mfma_f32_16x16x32_bf16(a0[mt], b0[nt], acc[mt][nt], 0, 0, 0);
                    acc[mt][nt] = __builtin_amdgcn_mfma_f32_16x16x32_bf16(a0[mt], b1[nt], acc[mt][nt], 0, 0, 0);
                    acc[mt][nt] = __builtin_amdgcn_mfma_f32_16x16x32_bf16(a1[mt], b0[nt], acc[mt][nt], 0, 0, 0);
                }
        } else {
#pragma unroll
            for (int mt = 0; mt < 4; ++mt)
#pragma unroll
                for (int nt = 0; nt < 4; ++nt)
                    acc[mt][nt] = __builtin_amdgcn_mfma_f32_16x16x32_bf16(a0[mt], b0[nt], acc[mt][nt], 0, 0, 0);
        }
    }

#pragma unroll
    for (int mt = 0; mt < 4; ++mt) {
#pragma unroll
        for (int r = 0; r < 4; ++r) {
            int oo = o0 + wr + mt * 16 + g * 4 + r;
            size_t rowbase = ((size_t)n * O + oo) * L_S;
#pragma unroll
            for (int nt = 0; nt < 4; ++nt) {
                int ll = l0 + wc + nt * 16 + c;
                if (OUT_BF16)
                    ((unsigned short*)Y)[rowbase + ll] = bf16_rn(acc[mt][nt][r]);
                else
                    ((float*)Y)[rowbase + ll] = acc[mt][nt][r];
            }
        }
    }
}

// ---------------------------------------------------------------------------
// Fused dwconv + l2norm + pack for Q/K heads, v2: LDS-staged stencil.
// grid: (L/256, 16, N). Stage [64 ch][258] bf16 window once (uint4 loads),
// taps read from LDS instead of 192 scalar global loads.
// ---------------------------------------------------------------------------
__global__ __launch_bounds__(256) void fused_qk2(const unsigned short* __restrict__ qkv_bf,
                                                 const float* __restrict__ w_dw,
                                                 unsigned short* __restrict__ Qb,
                                                 unsigned short* __restrict__ Kb) {
    __shared__ unsigned short rows[64 * 264];   // [e][264]: 0..255 main, 256=left halo, 257=right halo
    __shared__ float wsm[192];
    const int tid = threadIdx.x;
    const int l0  = blockIdx.x * 256;
    const int gg  = blockIdx.y;
    const int n   = blockIdx.z;
    const int head = gg & 7;
    const int ch0  = (gg < 8) ? head * 64 : 512 + head * 64;

    if (tid < 192) wsm[tid] = w_dw[ch0 * 3 + tid];

    const unsigned short* base = qkv_bf + ((size_t)n * C3 + ch0) * L_S;
    // stage main window: 64 rows x 32 uint4
    for (int f = tid; f < 2048; f += 256) {
        int e = f >> 5, s = f & 31;
        *(uint4*)&rows[e * 264 + s * 8] = *(const uint4*)&base[(size_t)e * L_S + l0 + s * 8];
    }
    // halos
    if (tid < 64) {
        rows[tid * 264 + 256] = (l0 > 0) ? base[(size_t)tid * L_S + l0 - 1] : (unsigned short)0;
    } else if (tid < 128) {
        int e = tid - 64;
        rows[e * 264 + 257] = (l0 + 256 < L_S) ? base[(size_t)e * L_S + l0 + 256] : (unsigned short)0;
    }
    __syncthreads();

    const int lL = tid;
    const int iL = (lL == 0)   ? 256 : lL - 1;
    const int iR = (lL == 255) ? 257 : lL + 1;
    float y[64];
    float s = 0.f;
#pragma unroll
    for (int e = 0; e < 64; ++e) {
        float a = bf16_f(rows[e * 264 + iL]);
        float b = bf16_f(rows[e * 264 + lL]);
        float d = bf16_f(rows[e * 264 + iR]);
        float v = wsm[e * 3 + 0] * a + wsm[e * 3 + 1] * b + wsm[e * 3 + 2] * d;
        y[e] = v;
        s += v * v;
    }
    float sc = 1.0f / fmaxf(sqrtf(s), 1e-12f);

    const int l = l0 + tid;
    unsigned short* dst = ((gg < 8) ? Qb : Kb) + (size_t)(n * H_N + head) * 8 * L_S * 8;
#pragma unroll
    for (int p = 0; p < 8; ++p) {
        uint4 pk = make_uint4(pk_bf16(y[8 * p + 0] * sc, y[8 * p + 1] * sc),
                              pk_bf16(y[8 * p + 2] * sc, y[8 * p + 3] * sc),
                              pk_bf16(y[8 * p + 4] * sc, y[8 * p + 5] * sc),
                              pk_bf16(y[8 * p + 6] * sc, y[8 * p + 7] * sc));
        *(uint4*)&dst[((size_t)p * L_S + l) * 8] = pk;
    }
}

// ---------------------------------------------------------------------------
// Fused dwconv + pack for V heads, v2: thread owns 8 consecutive keys of one
// channel -> 3 vector loads + 1 uint4 store. grid: (64, H, N).
// ---------------------------------------------------------------------------
__global__ __launch_bounds__(256) void fused_v2(const unsigned short* __restrict__ qkv_bf,
                                                const float* __restrict__ w_dw,
                                                unsigned short* __restrict__ Vb) {
    const int tid = threadIdx.x;
    const int e   = tid & 63;
    const int jp  = blockIdx.x * 4 + (tid >> 6);   // 0..255
    const int h   = blockIdx.y;
    const int n   = blockIdx.z;
    const int ch  = 1024 + h * 64 + e;
    const unsigned short* row = qkv_bf + ((size_t)n * C3 + ch) * L_S;
    const int k0 = jp * 8;

    uint4 mv = *(const uint4*)&row[k0];                                      // keys k0..k0+7
    unsigned int lw = (jp > 0)   ? *(const unsigned int*)&row[k0 - 2] : 0u;  // k0-2,k0-1
    unsigned int rw = (jp < 255) ? *(const unsigned int*)&row[k0 + 8] : 0u;  // k0+8,k0+9

    float v[10];
    v[0] = bf16_f((unsigned short)(lw >> 16));          // key k0-1
    v[1] = bf16_f((unsigned short)(mv.x & 0xFFFF));
    v[2] = bf16_f((unsigned short)(mv.x >> 16));
    v[3] = bf16_f((unsigned short)(mv.y & 0xFFFF));
    v[4] = bf16_f((unsigned short)(mv.y >> 16));
    v[5] = bf16_f((unsigned short)(mv.z & 0xFFFF));
    v[6] = bf16_f((unsigned short)(mv.z >> 16));
    v[7] = bf16_f((unsigned short)(mv.w & 0xFFFF));
    v[8] = bf16_f((unsigned short)(mv.w >> 16));
    v[9] = bf16_f((unsigned short)(rw & 0xFFFF));       // key k0+8

    float w0 = w_dw[ch * 3 + 0], w1 = w_dw[ch * 3 + 1], w2 = w_dw[ch * 3 + 2];
    unsigned int o[4];
#pragma unroll
    for (int i = 0; i < 4; ++i) {
        float y0 = w0 * v[2 * i + 0] + w1 * v[2 * i + 1] + w2 * v[2 * i + 2];
        float y1 = w0 * v[2 * i + 1] + w1 * v[2 * i + 2] + w2 * v[2 * i + 3];
        o[i] = pk_bf16(y0, y1);
    }
    uint4 ov = make_uint4(o[0], o[1], o[2], o[3]);
    *(uint4*)&Vb[(((size_t)(n * H_N + h) * 256 + jp) * 512) + e * 8] = ov;
}

// ---------------------------------------------------------------------------
// Flash attention v5: 32x32x16 swapped-QK^T, 2-chunk software pipeline
// (QKa, QKb, SMa, PVa, SMb, PVb, 1 barrier), P entirely in registers via
// cvt_pk + shfl_xor(32) half-wave exchange. grid: (L/128, H, N).
// ---------------------------------------------------------------------------
__global__ __launch_bounds__(256) void attn5(const unsigned short* __restrict__ Qb,
                                             const unsigned short* __restrict__ Kb,
                                             const unsigned short* __restrict__ Vb,
                                             const float* __restrict__ temp,
                                             unsigned short* __restrict__ ao_hi,
                                             unsigned short* __restrict__ ao_lo) {
    __shared__ unsigned short KV[32768];   // 64KB: buf[2] x {Ka,Va,Kb,Vb} x 4096 u16
    __shared__ float sm[128];
    float* Ot = (float*)KV;                // 128q x 64e f32 (32KB) after final barrier

    const int tid  = threadIdx.x;
    const int lane = tid & 63;
    const int w    = tid >> 6;
    const int c32  = lane & 31;
    const int h    = lane >> 5;
    const int q0   = blockIdx.x * 128;
    const int hd   = blockIdx.y;
    const int n    = blockIdx.z;

    const size_t hb = (size_t)(n * H_N + hd);
    const unsigned short* Qh = Qb + hb * 8 * L_S * 8;
    const unsigned short* Kh = Kb + hb * 8 * L_S * 8;
    const unsigned short* Vh = Vb + hb * 256 * 512;
    const float t     = temp[hd];
    const float t2    = t * 1.44269504088896f;
    const float negm2 = -fabsf(t2);

    // ---- prologue: Q into buf1 area; chunk pair 0 into buf0
    unsigned short* Qs = KV + 16384;
    {
        int idx = w * 4;
#pragma unroll
        for (int r = 0; r < 4; ++r) {
            int p = (idx + r) >> 1, hh = (idx + r) & 1;
            gll16(Qh + ((size_t)p * L_S + q0 + hh * 64 + lane) * 8, Qs + p * 1024 + hh * 512);
        }
        gll16(Kh + ((size_t)w * L_S + lane) * 8,              KV + w * 512);
        gll16(Kh + ((size_t)(w + 4) * L_S + lane) * 8,        KV + (w + 4) * 512);
        gll16(Vh + ((size_t)w * 512 + lane * 8),              KV + 4096 + w * 512);
        gll16(Vh + ((size_t)(w + 4) * 512 + lane * 8),        KV + 4096 + (w + 4) * 512);
        gll16(Kh + ((size_t)w * L_S + 64 + lane) * 8,         KV + 8192 + w * 512);
        gll16(Kh + ((size_t)(w + 4) * L_S + 64 + lane) * 8,   KV + 8192 + (w + 4) * 512);
        gll16(Vh + ((size_t)(8 + w) * 512 + lane * 8),        KV + 12288 + w * 512);
        gll16(Vh + ((size_t)(8 + w + 4) * 512 + lane * 8),    KV + 12288 + (w + 4) * 512);
    }
    __syncthreads();
    short8 qa[4];
#pragma unroll
    for (int es = 0; es < 4; ++es)
        qa[es] = *(short8*)&Qs[(es * 2 + h) * 1024 + (w * 32 + c32) * 8];
    __syncthreads();   // qa reads done before iter-0 prefetch overwrites Qs

    f32x16 acc0, acc1;
#pragma unroll
    for (int i = 0; i < 16; ++i) { acc0[i] = 0.f; acc1[i] = 0.f; }
    float sumP = 0.f;

// softmax + pack + half-wave exchange + A-frag assembly for one 64-key chunk
#define SM_BLOCK(SF0, SF1, PA)                                                  \
    {                                                                           \
        unsigned int W_[16], R_[16];                                            \
        _Pragma("unroll")                                                       \
        for (int G = 0; G < 4; ++G) {                                           \
            float p0 = exp2f(fmaf((SF0)[4*G+0], t2, negm2));                    \
            float p1 = exp2f(fmaf((SF0)[4*G+1], t2, negm2));                    \
            float p2 = exp2f(fmaf((SF0)[4*G+2], t2, negm2));                    \
            float p3 = exp2f(fmaf((SF0)[4*G+3], t2, negm2));                    \
            sumP += (p0 + p1) + (p2 + p3);                                      \
            W_[2*G]   = pk_bf16(p0, p1);                                        \
            W_[2*G+1] = pk_bf16(p2, p3);                                        \
            float u0 = exp2f(fmaf((SF1)[4*G+0], t2, negm2));                    \
            float u1 = exp2f(fmaf((SF1)[4*G+1], t2, negm2));                    \
            float u2 = exp2f(fmaf((SF1)[4*G+2], t2, negm2));                    \
            float u3 = exp2f(fmaf((SF1)[4*G+3], t2, negm2));                    \
            sumP += (u0 + u1) + (u2 + u3);                                      \
            W_[8+2*G]   = pk_bf16(u0, u1);                                      \
            W_[8+2*G+1] = pk_bf16(u2, u3);                                      \
        }                                                                       \
        _Pragma("unroll")                                                       \
        for (int j = 0; j < 16; ++j) R_[j] = __shfl_xor(W_[j], 32);             \
        _Pragma("unroll")                                                       \
        for (int ks = 0; ks < 4; ++ks) {                                        \
            const int bb = (ks >> 1) * 8;                                       \
            const int m4 = (ks & 1) * 4;                                        \
            unsigned int a0 = h ? R_[bb+m4+2] : W_[bb+m4+0];                    \
            unsigned int a1 = h ? R_[bb+m4+3] : W_[bb+m4+1];                    \
            unsigned int a2 = h ? W_[bb+m4+2] : R_[bb+m4+0];                    \
            unsigned int a3 = h ? W_[bb+m4+3] : R_[bb+m4+1];                    \
            uint4 pu = make_uint4(a0, a1, a2, a3);                              \
            (PA)[ks] = *(short8*)&pu;                                           \
        }                                                                       \
    }

    for (int it = 0; it < 16; ++it) {
        const int cur = it & 1;
        const unsigned short* B = KV + cur * 16384;

        if (it < 15) {   // prefetch next chunk pair into other buffer
            const int kb = (it + 1) * 128;
            unsigned short* D = KV + (cur ^ 1) * 16384;
            gll16(Kh + ((size_t)w * L_S + kb + lane) * 8,                D + w * 512);
            gll16(Kh + ((size_t)(w + 4) * L_S + kb + lane) * 8,          D + (w + 4) * 512);
            gll16(Vh + ((size_t)(kb / 8 + w) * 512 + lane * 8),          D + 4096 + w * 512);
            gll16(Vh + ((size_t)(kb / 8 + w + 4) * 512 + lane * 8),      D + 4096 + (w + 4) * 512);
            gll16(Kh + ((size_t)w * L_S + kb + 64 + lane) * 8,           D + 8192 + w * 512);
            gll16(Kh + ((size_t)(w + 4) * L_S + kb + 64 + lane) * 8,     D + 8192 + (w + 4) * 512);
            gll16(Vh + ((size_t)(kb / 8 + 8 + w) * 512 + lane * 8),      D + 12288 + w * 512);
            gll16(Vh + ((size_t)(kb / 8 + 8 + w + 4) * 512 + lane * 8),  D + 12288 + (w + 4) * 512);
        }

        // ---- QK(a)
        f32x16 sa0, sa1, sb0, sb1;
#pragma unroll
        for (int i = 0; i < 16; ++i) { sa0[i] = 0.f; sa1[i] = 0.f; sb0[i] = 0.f; sb1[i] = 0.f; }
#pragma unroll
        for (int es = 0; es < 4; ++es) {
            short8 k0f = *(short8*)&B[(es * 2 + h) * 512 + c32 * 8];
            short8 k1f = *(short8*)&B[(es * 2 + h) * 512 + (32 + c32) * 8];
            sa0 = __builtin_amdgcn_mfma_f32_32x32x16_bf16(k0f, qa[es], sa0, 0, 0, 0);
            sa1 = __builtin_amdgcn_mfma_f32_32x32x16_bf16(k1f, qa[es], sa1, 0, 0, 0);
        }
        // ---- QK(b)
#pragma unroll
        for (int es = 0; es < 4; ++es) {
            short8 k0f = *(short8*)&B[8192 + (es * 2 + h) * 512 + c32 * 8];
            short8 k1f = *(short8*)&B[8192 + (es * 2 + h) * 512 + (32 + c32) * 8];
            sb0 = __builtin_amdgcn_mfma_f32_32x32x16_bf16(k0f, qa[es], sb0, 0, 0, 0);
            sb1 = __builtin_amdgcn_mfma_f32_32x32x16_bf16(k1f, qa[es], sb1, 0, 0, 0);
        }

        // ---- SM(a) (VALU; overlaps QK(b) MFMA execution)
        short8 paA[4];
        SM_BLOCK(sa0, sa1, paA)

        // ---- PV(a)
#pragma unroll
        for (int ks = 0; ks < 4; ++ks) {
            short8 vb0 = *(short8*)&B[4096 + (ks * 2 + h) * 512 + c32 * 8];
            short8 vb1 = *(short8*)&B[4096 + (ks * 2 + h) * 512 + (32 + c32) * 8];
            acc0 = __builtin_amdgcn_mfma_f32_32x32x16_bf16(paA[ks], vb0, acc0, 0, 0, 0);
            acc1 = __builtin_amdgcn_mfma_f32_32x32x16_bf16(paA[ks], vb1, acc1, 0, 0, 0);
        }

        // ---- SM(b) (overlaps PV(a))
        short8 paB[4];
        SM_BLOCK(sb0, sb1, paB)

        // ---- PV(b)
#pragma unroll
        for (int ks = 0; ks < 4; ++ks) {
            short8 vb0 = *(short8*)&B[12288 + (ks * 2 + h) * 512 + c32 * 8];
            short8 vb1 = *(short8*)&B[12288 + (ks * 2 + h) * 512 + (32 + c32) * 8];
            acc0 = __builtin_amdgcn_mfma_f32_32x32x16_bf16(paB[ks], vb0, acc0, 0, 0, 0);
            acc1 = __builtin_amdgcn_mfma_f32_32x32x16_bf16(paB[ks], vb1, acc1, 0, 0, 0);
        }

        __syncthreads();   // drains prefetch vmcnt + protects buffer swap
    }
#undef SM_BLOCK

    // ---- final denominator
    sumP += __shfl_xor(sumP, 32);
    sm[w * 32 + c32] = 1.0f / sumP;

    float inv[16];
#pragma unroll
    for (int r = 0; r < 16; ++r) {
        int ql = (r & 3) + 8 * (r >> 2) + 4 * h;
        inv[r] = sm[w * 32 + ql];
    }

#pragma unroll
    for (int r = 0; r < 16; ++r) {
        int ql = (r & 3) + 8 * (r >> 2) + 4 * h;
        int qg = w * 32 + ql;
        Ot[qg * 64 + (c32 ^ (qg & 31))]        = acc0[r] * inv[r];
        Ot[qg * 64 + ((32 + c32) ^ (qg & 31))] = acc1[r] * inv[r];
    }
    __syncthreads();

    for (int tt = tid; tt < 8192; tt += 256) {
        int e = tt >> 7, qq = tt & 127;
        float v = Ot[qq * 64 + (e ^ (qq & 31))];
        unsigned short hi_ = bf16_rn(v);
        unsigned short lo_ = bf16_rn(v - bf16_f(hi_));
        size_t off = ((size_t)n * D_F + hd * 64 + e) * L_S + q0 + qq;
        ao_hi[off] = hi_;
        ao_lo[off] = lo_;
    }
}

// ---------------------------------------------------------------------------
extern "C" void kernel_launch(void* const* d_in, const int* in_sizes, int n_in,
                              void* d_out, int out_size, void* d_ws, size_t ws_size,
                              hipStream_t stream) {
    const float* x      = (const float*)d_in[0];   // (4, 512, 2048)
    const float* w_qkv  = (const float*)d_in[1];   // (1536, 512)
    const float* w_dw   = (const float*)d_in[2];   // (1536, 3)
    const float* w_proj = (const float*)d_in[3];   // (512, 512)
    const float* temp   = (const float*)d_in[4];   // (8)
    float* out = (float*)d_out;

    const size_t XE  = (size_t)N_B * D_F * L_S;    // 4,194,304
    const size_t WQE = (size_t)C3 * D_F;           // 786,432
    const size_t WPE = (size_t)D_F * D_F;          // 262,144

    char* ws = (char*)d_ws;
    unsigned short* qkv_bf = (unsigned short*)ws;               // 25,165,824 B
    unsigned short* Qb     = (unsigned short*)(ws + 25165824);  //  8,388,608 B
    unsigned short* Kb     = (unsigned short*)(ws + 33554432);  //  8,388,608 B
    unsigned short* Vb     = (unsigned short*)(ws + 41943040);  //  8,388,608 B
    unsigned short* x_hi   = (unsigned short*)(ws + 50331648);  //  8,388,608 B
    unsigned short* x_lo   = (unsigned short*)(ws + 58720256);  //  8,388,608 B
    unsigned short* wq_hi  = (unsigned short*)(ws + 67108864);  //  1,572,864 B
    unsigned short* wq_lo  = wq_hi + WQE;
    unsigned short* wp_hi  = (unsigned short*)(ws + 70254592);  //    524,288 B
    unsigned short* wp_lo  = wp_hi + WPE;                       // ends ~71.3 MB
    unsigned short* ao_hi  = x_hi;   // reuse (x consumed by QKV gemm)
    unsigned short* ao_lo  = x_lo;

    // 0) precision splits
    cvt_split<<<dim3((XE / 4 + 255) / 256), 256, 0, stream>>>(x, x_hi, x_lo, XE / 4);
    cvt_split<<<dim3((WQE / 4 + 255) / 256), 256, 0, stream>>>(w_qkv, wq_hi, wq_lo, WQE / 4);
    cvt_split<<<dim3((WPE / 4 + 255) / 256), 256, 0, stream>>>(w_proj, wp_hi, wp_lo, WPE / 4);

    // 1) QKV 1x1 conv: plain bf16 MFMA -> bf16
    gemm_mfma<0, 1><<<dim3(L_S / 128, C3 / 128, N_B), 256, 0, stream>>>(
        wq_hi, nullptr, x_hi, nullptr, qkv_bf, C3, D_F);

    // 2) fused dwconv (+l2norm) + MFMA-layout bf16 pack
    fused_qk2<<<dim3(L_S / 256, 16, N_B), 256, 0, stream>>>(qkv_bf, w_dw, Qb, Kb);
    fused_v2<<<dim3(64, H_N, N_B), 256, 0, stream>>>(qkv_bf, w_dw, Vb);

    // 3) attention (2-chunk pipelined, register-P) -> split bf16 hi/lo
    attn5<<<dim3(L_S / 128, H_N, N_B), 256, 0, stream>>>(Qb, Kb, Vb, temp, ao_hi, ao_lo);

    // 4) 3-term split-bf16 proj GEMM -> fp32 out
    gemm_mfma<1, 0><<<dim3(L_S / 128, D_F / 128, N_B), 256, 0, stream>>>(
        wp_hi, wp_lo, ao_hi, ao_lo, out, D_F, D_F);
}

// Round 8
// 159.820 us; speedup vs baseline: 1.6214x; 1.1236x over previous
//
#include <hip/hip_runtime.h>
#include <hip/hip_bf16.h>
#include <cstdint>
#include <cstddef>

#define N_B 4
#define D_F 512
#define L_S 2048
#define H_N 8
#define DH  64
#define C3  (3*D_F)   // 1536

typedef __attribute__((ext_vector_type(8)))  short short8;
typedef __attribute__((ext_vector_type(4)))  float f32x4;
typedef __attribute__((ext_vector_type(16))) float f32x16;

__device__ __forceinline__ unsigned int pk_bf16(float a, float b) {
    __hip_bfloat162 h = __float22bfloat162_rn(float2{a, b});
    union { __hip_bfloat162 h; unsigned int u; } cv;
    cv.h = h;
    return cv.u;
}
__device__ __forceinline__ unsigned short bf16_rn(float f) {
    union { float f; unsigned int u; } c; c.f = f;
    unsigned int r = c.u + 0x7FFF + ((c.u >> 16) & 1);
    return (unsigned short)(r >> 16);
}
__device__ __forceinline__ float bf16_f(unsigned short h) {
    union { unsigned int u; float f; } c; c.u = ((unsigned int)h) << 16;
    return c.f;
}

// async global->LDS, 16B per lane; lds base must be wave-uniform; global addr per-lane.
__device__ __forceinline__ void gll16(const unsigned short* g, unsigned short* l) {
    __builtin_amdgcn_global_load_lds(
        (const __attribute__((address_space(1))) unsigned int*)g,
        (__attribute__((address_space(3))) unsigned int*)l,
        16, 0, 0);
}

// ---------------------------------------------------------------------------
// Split fp32 -> bf16 hi + bf16 lo (weights only now)
// ---------------------------------------------------------------------------
__global__ __launch_bounds__(256) void cvt_split(const float* __restrict__ src,
                                                 unsigned short* __restrict__ hi,
                                                 unsigned short* __restrict__ lo,
                                                 int n4) {
    int i = blockIdx.x * 256 + threadIdx.x;
    if (i >= n4) return;
    float4 v = ((const float4*)src)[i];
    ushort4 h, l;
    h.x = bf16_rn(v.x); l.x = bf16_rn(v.x - bf16_f(h.x));
    h.y = bf16_rn(v.y); l.y = bf16_rn(v.y - bf16_f(h.y));
    h.z = bf16_rn(v.z); l.z = bf16_rn(v.z - bf16_f(h.z));
    h.w = bf16_rn(v.w); l.w = bf16_rn(v.w - bf16_f(h.w));
    ((ushort4*)hi)[i] = h;
    ((ushort4*)lo)[i] = l;
}

// ---------------------------------------------------------------------------
// Transpose+convert: x[n][c][l] f32 -> xT[n][l][c] bf16 (hi only).
// grid: (L/64, C/64, N), 256 threads, LDS 64x65 f32 tile.
// ---------------------------------------------------------------------------
__global__ __launch_bounds__(256) void cvt_xT(const float* __restrict__ x,
                                              unsigned short* __restrict__ xT,
                                              int C) {
    __shared__ float tile[64][65];
    const int tid = threadIdx.x;
    const int l0  = blockIdx.x * 64;
    const int c0  = blockIdx.y * 64;
    const int n   = blockIdx.z;

    const float* xn = x + (size_t)n * C * L_S;
#pragma unroll
    for (int r = 0; r < 16; ++r) {
        int c = r * 4 + (tid >> 6);
        int l = tid & 63;
        tile[c][l] = xn[(size_t)(c0 + c) * L_S + l0 + l];
    }
    __syncthreads();

    unsigned short* xn_t = xT + (size_t)n * L_S * C;
#pragma unroll
    for (int r = 0; r < 8; ++r) {
        int l  = r * 8 + (tid >> 5);
        int cp = tid & 31;
        unsigned int pk = pk_bf16(tile[cp * 2][l], tile[cp * 2 + 1][l]);
        *(unsigned int*)&xn_t[(size_t)(l0 + l) * C + c0 + cp * 2] = pk;
    }
}

// ---------------------------------------------------------------------------
// MFMA GEMM v2: Y[n][o][l] = sum_c W[o][c] * X[c][l], X given TRANSPOSED as
// XT[n][l][c] (c contiguous). Both tiles staged via global_load_lds (zero
// staging VALU). Tile 128o x 128l, BK=32, 4 waves. grid: (L/128, O/128, N).
// ---------------------------------------------------------------------------
template<int SPLIT, int OUT_BF16>
__global__ __launch_bounds__(256) void gemm_mfma2(const unsigned short* __restrict__ Whi,
                                                  const unsigned short* __restrict__ Wlo,
                                                  const unsigned short* __restrict__ XThi,
                                                  const unsigned short* __restrict__ XTlo,
                                                  void* __restrict__ Y,
                                                  int O, int C) {
    __shared__ unsigned short Wt[SPLIT ? 2 : 1][4][128 * 8];
    __shared__ unsigned short Xt[SPLIT ? 2 : 1][4][128 * 8];

    const int tid  = threadIdx.x;
    const int lane = tid & 63;
    const int w    = tid >> 6;
    const int g    = lane >> 4;
    const int c    = lane & 15;
    const int wr   = (w >> 1) * 64;
    const int wc   = (w & 1) * 64;
    const int l0   = blockIdx.x * 128;
    const int o0   = blockIdx.y * 128;
    const int n    = blockIdx.z;

    const unsigned short* XTn_hi = XThi + (size_t)n * L_S * C;
    const unsigned short* XTn_lo = SPLIT ? (XTlo + (size_t)n * L_S * C) : nullptr;

    // wave staging geometry: rows (w&1)*64 + lane; planes cpA = w>>1, cpB = 2+(w>>1)
    const int rhalf = (w & 1) * 64;
    const int cpA   = w >> 1;
    const int cpB   = 2 + (w >> 1);
    const size_t wrowA = (size_t)(o0 + rhalf + lane) * C;
    const size_t xrowA = (size_t)(l0 + rhalf + lane) * C;

    f32x4 acc[4][4];
#pragma unroll
    for (int mt = 0; mt < 4; ++mt)
#pragma unroll
        for (int nt = 0; nt < 4; ++nt) acc[mt][nt] = (f32x4){0.f, 0.f, 0.f, 0.f};

    for (int c0 = 0; c0 < C; c0 += 32) {
        __syncthreads();   // prev iter's frag reads done
        gll16(Whi + wrowA + c0 + cpA * 8, &Wt[0][cpA][rhalf * 8]);
        gll16(Whi + wrowA + c0 + cpB * 8, &Wt[0][cpB][rhalf * 8]);
        gll16(XTn_hi + xrowA + c0 + cpA * 8, &Xt[0][cpA][rhalf * 8]);
        gll16(XTn_hi + xrowA + c0 + cpB * 8, &Xt[0][cpB][rhalf * 8]);
        if (SPLIT) {
            gll16(Wlo + wrowA + c0 + cpA * 8, &Wt[1][cpA][rhalf * 8]);
            gll16(Wlo + wrowA + c0 + cpB * 8, &Wt[1][cpB][rhalf * 8]);
            gll16(XTn_lo + xrowA + c0 + cpA * 8, &Xt[1][cpA][rhalf * 8]);
            gll16(XTn_lo + xrowA + c0 + cpB * 8, &Xt[1][cpB][rhalf * 8]);
        }
        __syncthreads();   // drains gll16 vmcnt

        short8 a0[4], b0[4];
#pragma unroll
        for (int mt = 0; mt < 4; ++mt) a0[mt] = *(short8*)&Wt[0][g][(wr + mt * 16 + c) * 8];
#pragma unroll
        for (int nt = 0; nt < 4; ++nt) b0[nt] = *(short8*)&Xt[0][g][(wc + nt * 16 + c) * 8];

        if (SPLIT) {
            short8 a1[4], b1[4];
#pragma unroll
            for (int mt = 0; mt < 4; ++mt) a1[mt] = *(short8*)&Wt[1][g][(wr + mt * 16 + c) * 8];
#pragma unroll
            for (int nt = 0; nt < 4; ++nt) b1[nt] = *(short8*)&Xt[1][g][(wc + nt * 16 + c) * 8];
#pragma unroll
            for (int mt = 0; mt < 4; ++mt)
#pragma unroll
                for (int nt = 0; nt < 4; ++nt) {
                    acc[mt][nt] = __builtin_amdgcn_mfma_f32_16x16x32_bf16(a0[mt], b0[nt], acc[mt][nt], 0, 0, 0);
                    acc[mt][nt] = __builtin_amdgcn_mfma_f32_16x16x32_bf16(a0[mt], b1[nt], acc[mt][nt], 0, 0, 0);
                    acc[mt][nt] = __builtin_amdgcn_mfma_f32_16x16x32_bf16(a1[mt], b0[nt], acc[mt][nt], 0, 0, 0);
                }
        } else {
#pragma unroll
            for (int mt = 0; mt < 4; ++mt)
#pragma unroll
                for (int nt = 0; nt < 4; ++nt)
                    acc[mt][nt] = __builtin_amdgcn_mfma_f32_16x16x32_bf16(a0[mt], b0[nt], acc[mt][nt], 0, 0, 0);
        }
    }

#pragma unroll
    for (int mt = 0; mt < 4; ++mt) {
#pragma unroll
        for (int r = 0; r < 4; ++r) {
            int oo = o0 + wr + mt * 16 + g * 4 + r;
            size_t rowbase = ((size_t)n * O + oo) * L_S;
#pragma unroll
            for (int nt = 0; nt < 4; ++nt) {
                int ll = l0 + wc + nt * 16 + c;
                if (OUT_BF16)
                    ((unsigned short*)Y)[rowbase + ll] = bf16_rn(acc[mt][nt][r]);
                else
                    ((float*)Y)[rowbase + ll] = acc[mt][nt][r];
            }
        }
    }
}

// ---------------------------------------------------------------------------
// Fused dwconv + l2norm + pack for Q/K heads (unchanged from R7).
// ---------------------------------------------------------------------------
__global__ __launch_bounds__(256) void fused_qk2(const unsigned short* __restrict__ qkv_bf,
                                                 const float* __restrict__ w_dw,
                                                 unsigned short* __restrict__ Qb,
                                                 unsigned short* __restrict__ Kb) {
    __shared__ unsigned short rows[64 * 264];
    __shared__ float wsm[192];
    const int tid = threadIdx.x;
    const int l0  = blockIdx.x * 256;
    const int gg  = blockIdx.y;
    const int n   = blockIdx.z;
    const int head = gg & 7;
    const int ch0  = (gg < 8) ? head * 64 : 512 + head * 64;

    if (tid < 192) wsm[tid] = w_dw[ch0 * 3 + tid];

    const unsigned short* base = qkv_bf + ((size_t)n * C3 + ch0) * L_S;
    for (int f = tid; f < 2048; f += 256) {
        int e = f >> 5, s = f & 31;
        *(uint4*)&rows[e * 264 + s * 8] = *(const uint4*)&base[(size_t)e * L_S + l0 + s * 8];
    }
    if (tid < 64) {
        rows[tid * 264 + 256] = (l0 > 0) ? base[(size_t)tid * L_S + l0 - 1] : (unsigned short)0;
    } else if (tid < 128) {
        int e = tid - 64;
        rows[e * 264 + 257] = (l0 + 256 < L_S) ? base[(size_t)e * L_S + l0 + 256] : (unsigned short)0;
    }
    __syncthreads();

    const int lL = tid;
    const int iL = (lL == 0)   ? 256 : lL - 1;
    const int iR = (lL == 255) ? 257 : lL + 1;
    float y[64];
    float s = 0.f;
#pragma unroll
    for (int e = 0; e < 64; ++e) {
        float a = bf16_f(rows[e * 264 + iL]);
        float b = bf16_f(rows[e * 264 + lL]);
        float d = bf16_f(rows[e * 264 + iR]);
        float v = wsm[e * 3 + 0] * a + wsm[e * 3 + 1] * b + wsm[e * 3 + 2] * d;
        y[e] = v;
        s += v * v;
    }
    float sc = 1.0f / fmaxf(sqrtf(s), 1e-12f);

    const int l = l0 + tid;
    unsigned short* dst = ((gg < 8) ? Qb : Kb) + (size_t)(n * H_N + head) * 8 * L_S * 8;
#pragma unroll
    for (int p = 0; p < 8; ++p) {
        uint4 pk = make_uint4(pk_bf16(y[8 * p + 0] * sc, y[8 * p + 1] * sc),
                              pk_bf16(y[8 * p + 2] * sc, y[8 * p + 3] * sc),
                              pk_bf16(y[8 * p + 4] * sc, y[8 * p + 5] * sc),
                              pk_bf16(y[8 * p + 6] * sc, y[8 * p + 7] * sc));
        *(uint4*)&dst[((size_t)p * L_S + l) * 8] = pk;
    }
}

// ---------------------------------------------------------------------------
// Fused dwconv + pack for V heads (unchanged from R7).
// ---------------------------------------------------------------------------
__global__ __launch_bounds__(256) void fused_v2(const unsigned short* __restrict__ qkv_bf,
                                                const float* __restrict__ w_dw,
                                                unsigned short* __restrict__ Vb) {
    const int tid = threadIdx.x;
    const int e   = tid & 63;
    const int jp  = blockIdx.x * 4 + (tid >> 6);
    const int h   = blockIdx.y;
    const int n   = blockIdx.z;
    const int ch  = 1024 + h * 64 + e;
    const unsigned short* row = qkv_bf + ((size_t)n * C3 + ch) * L_S;
    const int k0 = jp * 8;

    uint4 mv = *(const uint4*)&row[k0];
    unsigned int lw = (jp > 0)   ? *(const unsigned int*)&row[k0 - 2] : 0u;
    unsigned int rw = (jp < 255) ? *(const unsigned int*)&row[k0 + 8] : 0u;

    float v[10];
    v[0] = bf16_f((unsigned short)(lw >> 16));
    v[1] = bf16_f((unsigned short)(mv.x & 0xFFFF));
    v[2] = bf16_f((unsigned short)(mv.x >> 16));
    v[3] = bf16_f((unsigned short)(mv.y & 0xFFFF));
    v[4] = bf16_f((unsigned short)(mv.y >> 16));
    v[5] = bf16_f((unsigned short)(mv.z & 0xFFFF));
    v[6] = bf16_f((unsigned short)(mv.z >> 16));
    v[7] = bf16_f((unsigned short)(mv.w & 0xFFFF));
    v[8] = bf16_f((unsigned short)(mv.w >> 16));
    v[9] = bf16_f((unsigned short)(rw & 0xFFFF));

    float w0 = w_dw[ch * 3 + 0], w1 = w_dw[ch * 3 + 1], w2 = w_dw[ch * 3 + 2];
    unsigned int o[4];
#pragma unroll
    for (int i = 0; i < 4; ++i) {
        float y0 = w0 * v[2 * i + 0] + w1 * v[2 * i + 1] + w2 * v[2 * i + 2];
        float y1 = w0 * v[2 * i + 1] + w1 * v[2 * i + 2] + w2 * v[2 * i + 3];
        o[i] = pk_bf16(y0, y1);
    }
    uint4 ov = make_uint4(o[0], o[1], o[2], o[3]);
    *(uint4*)&Vb[(((size_t)(n * H_N + h) * 256 + jp) * 512) + e * 8] = ov;
}

// ---------------------------------------------------------------------------
// Flash attention v6 = v5 structure + __expf (native v_exp) + transposed
// aoT[n][l][d] hi/lo output. grid: (L/128, H, N).
// ---------------------------------------------------------------------------
__global__ __launch_bounds__(256) void attn6(const unsigned short* __restrict__ Qb,
                                             const unsigned short* __restrict__ Kb,
                                             const unsigned short* __restrict__ Vb,
                                             const float* __restrict__ temp,
                                             unsigned short* __restrict__ aoT_hi,
                                             unsigned short* __restrict__ aoT_lo) {
    __shared__ unsigned short KV[32768];   // 64KB: buf[2] x {Ka,Va,Kb,Vb}
    __shared__ float sm[128];
    float* Ot = (float*)KV;

    const int tid  = threadIdx.x;
    const int lane = tid & 63;
    const int w    = tid >> 6;
    const int c32  = lane & 31;
    const int h    = lane >> 5;
    const int q0   = blockIdx.x * 128;
    const int hd   = blockIdx.y;
    const int n    = blockIdx.z;

    const size_t hb = (size_t)(n * H_N + hd);
    const unsigned short* Qh = Qb + hb * 8 * L_S * 8;
    const unsigned short* Kh = Kb + hb * 8 * L_S * 8;
    const unsigned short* Vh = Vb + hb * 256 * 512;
    const float t    = temp[hd];
    const float negm = -fabsf(t);

    unsigned short* Qs = KV + 16384;
    {
        int idx = w * 4;
#pragma unroll
        for (int r = 0; r < 4; ++r) {
            int p = (idx + r) >> 1, hh = (idx + r) & 1;
            gll16(Qh + ((size_t)p * L_S + q0 + hh * 64 + lane) * 8, Qs + p * 1024 + hh * 512);
        }
        gll16(Kh + ((size_t)w * L_S + lane) * 8,              KV + w * 512);
        gll16(Kh + ((size_t)(w + 4) * L_S + lane) * 8,        KV + (w + 4) * 512);
        gll16(Vh + ((size_t)w * 512 + lane * 8),              KV + 4096 + w * 512);
        gll16(Vh + ((size_t)(w + 4) * 512 + lane * 8),        KV + 4096 + (w + 4) * 512);
        gll16(Kh + ((size_t)w * L_S + 64 + lane) * 8,         KV + 8192 + w * 512);
        gll16(Kh + ((size_t)(w + 4) * L_S + 64 + lane) * 8,   KV + 8192 + (w + 4) * 512);
        gll16(Vh + ((size_t)(8 + w) * 512 + lane * 8),        KV + 12288 + w * 512);
        gll16(Vh + ((size_t)(8 + w + 4) * 512 + lane * 8),    KV + 12288 + (w + 4) * 512);
    }
    __syncthreads();
    short8 qa[4];
#pragma unroll
    for (int es = 0; es < 4; ++es)
        qa[es] = *(short8*)&Qs[(es * 2 + h) * 1024 + (w * 32 + c32) * 8];
    __syncthreads();

    f32x16 acc0, acc1;
#pragma unroll
    for (int i = 0; i < 16; ++i) { acc0[i] = 0.f; acc1[i] = 0.f; }
    float sumP = 0.f;

#define SM_BLOCK(SF0, SF1, PA)                                                  \
    {                                                                           \
        unsigned int W_[16], R_[16];                                            \
        _Pragma("unroll")                                                       \
        for (int G = 0; G < 4; ++G) {                                           \
            float p0 = __expf(fmaf((SF0)[4*G+0], t, negm));                     \
            float p1 = __expf(fmaf((SF0)[4*G+1], t, negm));                     \
            float p2 = __expf(fmaf((SF0)[4*G+2], t, negm));                     \
            float p3 = __expf(fmaf((SF0)[4*G+3], t, negm));                     \
            sumP += (p0 + p1) + (p2 + p3);                                      \
            W_[2*G]   = pk_bf16(p0, p1);                                        \
            W_[2*G+1] = pk_bf16(p2, p3);                                        \
            float u0 = __expf(fmaf((SF1)[4*G+0], t, negm));                     \
            float u1 = __expf(fmaf((SF1)[4*G+1], t, negm));                     \
            float u2 = __expf(fmaf((SF1)[4*G+2], t, negm));                     \
            float u3 = __expf(fmaf((SF1)[4*G+3], t, negm));                     \
            sumP += (u0 + u1) + (u2 + u3);                                      \
            W_[8+2*G]   = pk_bf16(u0, u1);                                      \
            W_[8+2*G+1] = pk_bf16(u2, u3);                                      \
        }                                                                       \
        _Pragma("unroll")                                                       \
        for (int j = 0; j < 16; ++j) R_[j] = __shfl_xor(W_[j], 32);             \
        _Pragma("unroll")                                                       \
        for (int ks = 0; ks < 4; ++ks) {                                        \
            const int bb = (ks >> 1) * 8;                                       \
            const int m4 = (ks & 1) * 4;                                        \
            unsigned int a0 = h ? R_[bb+m4+2] : W_[bb+m4+0];                    \
            unsigned int a1 = h ? R_[bb+m4+3] : W_[bb+m4+1];                    \
            unsigned int a2 = h ? W_[bb+m4+2] : R_[bb+m4+0];                    \
            unsigned int a3 = h ? W_[bb+m4+3] : R_[bb+m4+1];                    \
            uint4 pu = make_uint4(a0, a1, a2, a3);                              \
            (PA)[ks] = *(short8*)&pu;                                           \
        }                                                                       \
    }

    for (int it = 0; it < 16; ++it) {
        const int cur = it & 1;
        const unsigned short* B = KV + cur * 16384;

        if (it < 15) {
            const int kb = (it + 1) * 128;
            unsigned short* D = KV + (cur ^ 1) * 16384;
            gll16(Kh + ((size_t)w * L_S + kb + lane) * 8,                D + w * 512);
            gll16(Kh + ((size_t)(w + 4) * L_S + kb + lane) * 8,          D + (w + 4) * 512);
            gll16(Vh + ((size_t)(kb / 8 + w) * 512 + lane * 8),          D + 4096 + w * 512);
            gll16(Vh + ((size_t)(kb / 8 + w + 4) * 512 + lane * 8),      D + 4096 + (w + 4) * 512);
            gll16(Kh + ((size_t)w * L_S + kb + 64 + lane) * 8,           D + 8192 + w * 512);
            gll16(Kh + ((size_t)(w + 4) * L_S + kb + 64 + lane) * 8,     D + 8192 + (w + 4) * 512);
            gll16(Vh + ((size_t)(kb / 8 + 8 + w) * 512 + lane * 8),      D + 12288 + w * 512);
            gll16(Vh + ((size_t)(kb / 8 + 8 + w + 4) * 512 + lane * 8),  D + 12288 + (w + 4) * 512);
        }

        f32x16 sa0, sa1, sb0, sb1;
#pragma unroll
        for (int i = 0; i < 16; ++i) { sa0[i] = 0.f; sa1[i] = 0.f; sb0[i] = 0.f; sb1[i] = 0.f; }
#pragma unroll
        for (int es = 0; es < 4; ++es) {
            short8 k0f = *(short8*)&B[(es * 2 + h) * 512 + c32 * 8];
            short8 k1f = *(short8*)&B[(es * 2 + h) * 512 + (32 + c32) * 8];
            sa0 = __builtin_amdgcn_mfma_f32_32x32x16_bf16(k0f, qa[es], sa0, 0, 0, 0);
            sa1 = __builtin_amdgcn_mfma_f32_32x32x16_bf16(k1f, qa[es], sa1, 0, 0, 0);
        }
#pragma unroll
        for (int es = 0; es < 4; ++es) {
            short8 k0f = *(short8*)&B[8192 + (es * 2 + h) * 512 + c32 * 8];
            short8 k1f = *(short8*)&B[8192 + (es * 2 + h) * 512 + (32 + c32) * 8];
            sb0 = __builtin_amdgcn_mfma_f32_32x32x16_bf16(k0f, qa[es], sb0, 0, 0, 0);
            sb1 = __builtin_amdgcn_mfma_f32_32x32x16_bf16(k1f, qa[es], sb1, 0, 0, 0);
        }

        short8 paA[4];
        SM_BLOCK(sa0, sa1, paA)

#pragma unroll
        for (int ks = 0; ks < 4; ++ks) {
            short8 vb0 = *(short8*)&B[4096 + (ks * 2 + h) * 512 + c32 * 8];
            short8 vb1 = *(short8*)&B[4096 + (ks * 2 + h) * 512 + (32 + c32) * 8];
            acc0 = __builtin_amdgcn_mfma_f32_32x32x16_bf16(paA[ks], vb0, acc0, 0, 0, 0);
            acc1 = __builtin_amdgcn_mfma_f32_32x32x16_bf16(paA[ks], vb1, acc1, 0, 0, 0);
        }

        short8 paB[4];
        SM_BLOCK(sb0, sb1, paB)

#pragma unroll
        for (int ks = 0; ks < 4; ++ks) {
            short8 vb0 = *(short8*)&B[12288 + (ks * 2 + h) * 512 + c32 * 8];
            short8 vb1 = *(short8*)&B[12288 + (ks * 2 + h) * 512 + (32 + c32) * 8];
            acc0 = __builtin_amdgcn_mfma_f32_32x32x16_bf16(paB[ks], vb0, acc0, 0, 0, 0);
            acc1 = __builtin_amdgcn_mfma_f32_32x32x16_bf16(paB[ks], vb1, acc1, 0, 0, 0);
        }

        __syncthreads();
    }
#undef SM_BLOCK

    sumP += __shfl_xor(sumP, 32);
    sm[w * 32 + c32] = 1.0f / sumP;

    float inv[16];
#pragma unroll
    for (int r = 0; r < 16; ++r) {
        int ql = (r & 3) + 8 * (r >> 2) + 4 * h;
        inv[r] = sm[w * 32 + ql];
    }

#pragma unroll
    for (int r = 0; r < 16; ++r) {
        int ql = (r & 3) + 8 * (r >> 2) + 4 * h;
        int qg = w * 32 + ql;
        Ot[qg * 64 + (c32 ^ (qg & 31))]        = acc0[r] * inv[r];
        Ot[qg * 64 + ((32 + c32) ^ (qg & 31))] = acc1[r] * inv[r];
    }
    __syncthreads();

    // transposed output: aoT[n][l][d], d = hd*64 + e (e lane-contiguous)
    for (int tt = tid; tt < 8192; tt += 256) {
        int qq = tt >> 6, e = tt & 63;
        float v = Ot[qq * 64 + (e ^ (qq & 31))];
        unsigned short hi_ = bf16_rn(v);
        unsigned short lo_ = bf16_rn(v - bf16_f(hi_));
        size_t off = ((size_t)n * L_S + q0 + qq) * D_F + hd * 64 + e;
        aoT_hi[off] = hi_;
        aoT_lo[off] = lo_;
    }
}

// ---------------------------------------------------------------------------
extern "C" void kernel_launch(void* const* d_in, const int* in_sizes, int n_in,
                              void* d_out, int out_size, void* d_ws, size_t ws_size,
                              hipStream_t stream) {
    const float* x      = (const float*)d_in[0];   // (4, 512, 2048)
    const float* w_qkv  = (const float*)d_in[1];   // (1536, 512)
    const float* w_dw   = (const float*)d_in[2];   // (1536, 3)
    const float* w_proj = (const float*)d_in[3];   // (512, 512)
    const float* temp   = (const float*)d_in[4];   // (8)
    float* out = (float*)d_out;

    const size_t WQE = (size_t)C3 * D_F;           // 786,432
    const size_t WPE = (size_t)D_F * D_F;          // 262,144

    char* ws = (char*)d_ws;
    unsigned short* qkv_bf = (unsigned short*)ws;               // 25,165,824 B
    unsigned short* Qb     = (unsigned short*)(ws + 25165824);  //  8,388,608 B
    unsigned short* Kb     = (unsigned short*)(ws + 33554432);  //  8,388,608 B
    unsigned short* Vb     = (unsigned short*)(ws + 41943040);  //  8,388,608 B
    unsigned short* xT     = (unsigned short*)(ws + 50331648);  //  8,388,608 B
    unsigned short* aoT_lo = (unsigned short*)(ws + 58720256);  //  8,388,608 B
    unsigned short* wq_hi  = (unsigned short*)(ws + 67108864);  //  1,572,864 B
    unsigned short* wq_lo  = wq_hi + WQE;
    unsigned short* wp_hi  = (unsigned short*)(ws + 70254592);  //    524,288 B
    unsigned short* wp_lo  = wp_hi + WPE;                       // ends ~71.3 MB
    unsigned short* aoT_hi = xT;   // reuse: xT consumed by QKV gemm before attn writes

    // 0) weight splits + x transpose/convert
    cvt_xT<<<dim3(L_S / 64, D_F / 64, N_B), 256, 0, stream>>>(x, xT, D_F);
    cvt_split<<<dim3((WQE / 4 + 255) / 256), 256, 0, stream>>>(w_qkv, wq_hi, wq_lo, WQE / 4);
    cvt_split<<<dim3((WPE / 4 + 255) / 256), 256, 0, stream>>>(w_proj, wp_hi, wp_lo, WPE / 4);

    // 1) QKV 1x1 conv: bf16 MFMA, gll16-staged -> bf16
    gemm_mfma2<0, 1><<<dim3(L_S / 128, C3 / 128, N_B), 256, 0, stream>>>(
        wq_hi, nullptr, xT, nullptr, qkv_bf, C3, D_F);

    // 2) fused dwconv (+l2norm) + MFMA-layout bf16 pack
    fused_qk2<<<dim3(L_S / 256, 16, N_B), 256, 0, stream>>>(qkv_bf, w_dw, Qb, Kb);
    fused_v2<<<dim3(64, H_N, N_B), 256, 0, stream>>>(qkv_bf, w_dw, Vb);

    // 3) attention -> transposed split bf16 hi/lo
    attn6<<<dim3(L_S / 128, H_N, N_B), 256, 0, stream>>>(Qb, Kb, Vb, temp, aoT_hi, aoT_lo);

    // 4) 3-term split-bf16 proj GEMM (gll16-staged) -> fp32 out
    gemm_mfma2<1, 0><<<dim3(L_S / 128, D_F / 128, N_B), 256, 0, stream>>>(
        wp_hi, wp_lo, aoT_hi, aoT_lo, out, D_F, D_F);
}

// Round 9
// 152.234 us; speedup vs baseline: 1.7022x; 1.0498x over previous
//
#include <hip/hip_runtime.h>
#include <hip/hip_bf16.h>
#include <cstdint>
#include <cstddef>

#define N_B 4
#define D_F 512
#define L_S 2048
#define H_N 8
#define DH  64
#define C3  (3*D_F)   // 1536

typedef __attribute__((ext_vector_type(8)))  short short8;
typedef __attribute__((ext_vector_type(4)))  float f32x4;
typedef __attribute__((ext_vector_type(16))) float f32x16;

__device__ __forceinline__ unsigned int pk_bf16(float a, float b) {
    __hip_bfloat162 h = __float22bfloat162_rn(float2{a, b});
    union { __hip_bfloat162 h; unsigned int u; } cv;
    cv.h = h;
    return cv.u;
}
__device__ __forceinline__ unsigned short bf16_rn(float f) {
    union { float f; unsigned int u; } c; c.f = f;
    unsigned int r = c.u + 0x7FFF + ((c.u >> 16) & 1);
    return (unsigned short)(r >> 16);
}
__device__ __forceinline__ float bf16_f(unsigned short h) {
    union { unsigned int u; float f; } c; c.u = ((unsigned int)h) << 16;
    return c.f;
}

// async global->LDS, 16B per lane; lds base must be wave-uniform; global addr per-lane.
__device__ __forceinline__ void gll16(const unsigned short* g, unsigned short* l) {
    __builtin_amdgcn_global_load_lds(
        (const __attribute__((address_space(1))) unsigned int*)g,
        (__attribute__((address_space(3))) unsigned int*)l,
        16, 0, 0);
}

// ---------------------------------------------------------------------------
// Split fp32 -> bf16 hi + bf16 lo (weights only)
// ---------------------------------------------------------------------------
__global__ __launch_bounds__(256) void cvt_split(const float* __restrict__ src,
                                                 unsigned short* __restrict__ hi,
                                                 unsigned short* __restrict__ lo,
                                                 int n4) {
    int i = blockIdx.x * 256 + threadIdx.x;
    if (i >= n4) return;
    float4 v = ((const float4*)src)[i];
    ushort4 h, l;
    h.x = bf16_rn(v.x); l.x = bf16_rn(v.x - bf16_f(h.x));
    h.y = bf16_rn(v.y); l.y = bf16_rn(v.y - bf16_f(h.y));
    h.z = bf16_rn(v.z); l.z = bf16_rn(v.z - bf16_f(h.z));
    h.w = bf16_rn(v.w); l.w = bf16_rn(v.w - bf16_f(h.w));
    ((ushort4*)hi)[i] = h;
    ((ushort4*)lo)[i] = l;
}

// ---------------------------------------------------------------------------
// Transpose+convert: x[n][c][l] f32 -> xT[n][l][c] bf16 (unchanged).
// ---------------------------------------------------------------------------
__global__ __launch_bounds__(256) void cvt_xT(const float* __restrict__ x,
                                              unsigned short* __restrict__ xT,
                                              int C) {
    __shared__ float tile[64][65];
    const int tid = threadIdx.x;
    const int l0  = blockIdx.x * 64;
    const int c0  = blockIdx.y * 64;
    const int n   = blockIdx.z;

    const float* xn = x + (size_t)n * C * L_S;
#pragma unroll
    for (int r = 0; r < 16; ++r) {
        int c = r * 4 + (tid >> 6);
        int l = tid & 63;
        tile[c][l] = xn[(size_t)(c0 + c) * L_S + l0 + l];
    }
    __syncthreads();

    unsigned short* xn_t = xT + (size_t)n * L_S * C;
#pragma unroll
    for (int r = 0; r < 8; ++r) {
        int l  = r * 8 + (tid >> 5);
        int cp = tid & 31;
        unsigned int pk = pk_bf16(tile[cp * 2][l], tile[cp * 2 + 1][l]);
        *(unsigned int*)&xn_t[(size_t)(l0 + l) * C + c0 + cp * 2] = pk;
    }
}

// ---------------------------------------------------------------------------
// MFMA GEMM v2 (unchanged from R8).
// ---------------------------------------------------------------------------
template<int SPLIT, int OUT_BF16>
__global__ __launch_bounds__(256) void gemm_mfma2(const unsigned short* __restrict__ Whi,
                                                  const unsigned short* __restrict__ Wlo,
                                                  const unsigned short* __restrict__ XThi,
                                                  const unsigned short* __restrict__ XTlo,
                                                  void* __restrict__ Y,
                                                  int O, int C) {
    __shared__ unsigned short Wt[SPLIT ? 2 : 1][4][128 * 8];
    __shared__ unsigned short Xt[SPLIT ? 2 : 1][4][128 * 8];

    const int tid  = threadIdx.x;
    const int lane = tid & 63;
    const int w    = tid >> 6;
    const int g    = lane >> 4;
    const int c    = lane & 15;
    const int wr   = (w >> 1) * 64;
    const int wc   = (w & 1) * 64;
    const int l0   = blockIdx.x * 128;
    const int o0   = blockIdx.y * 128;
    const int n    = blockIdx.z;

    const unsigned short* XTn_hi = XThi + (size_t)n * L_S * C;
    const unsigned short* XTn_lo = SPLIT ? (XTlo + (size_t)n * L_S * C) : nullptr;

    const int rhalf = (w & 1) * 64;
    const int cpA   = w >> 1;
    const int cpB   = 2 + (w >> 1);
    const size_t wrowA = (size_t)(o0 + rhalf + lane) * C;
    const size_t xrowA = (size_t)(l0 + rhalf + lane) * C;

    f32x4 acc[4][4];
#pragma unroll
    for (int mt = 0; mt < 4; ++mt)
#pragma unroll
        for (int nt = 0; nt < 4; ++nt) acc[mt][nt] = (f32x4){0.f, 0.f, 0.f, 0.f};

    for (int c0 = 0; c0 < C; c0 += 32) {
        __syncthreads();
        gll16(Whi + wrowA + c0 + cpA * 8, &Wt[0][cpA][rhalf * 8]);
        gll16(Whi + wrowA + c0 + cpB * 8, &Wt[0][cpB][rhalf * 8]);
        gll16(XTn_hi + xrowA + c0 + cpA * 8, &Xt[0][cpA][rhalf * 8]);
        gll16(XTn_hi + xrowA + c0 + cpB * 8, &Xt[0][cpB][rhalf * 8]);
        if (SPLIT) {
            gll16(Wlo + wrowA + c0 + cpA * 8, &Wt[1][cpA][rhalf * 8]);
            gll16(Wlo + wrowA + c0 + cpB * 8, &Wt[1][cpB][rhalf * 8]);
            gll16(XTn_lo + xrowA + c0 + cpA * 8, &Xt[1][cpA][rhalf * 8]);
            gll16(XTn_lo + xrowA + c0 + cpB * 8, &Xt[1][cpB][rhalf * 8]);
        }
        __syncthreads();

        short8 a0[4], b0[4];
#pragma unroll
        for (int mt = 0; mt < 4; ++mt) a0[mt] = *(short8*)&Wt[0][g][(wr + mt * 16 + c) * 8];
#pragma unroll
        for (int nt = 0; nt < 4; ++nt) b0[nt] = *(short8*)&Xt[0][g][(wc + nt * 16 + c) * 8];

        if (SPLIT) {
            short8 a1[4], b1[4];
#pragma unroll
            for (int mt = 0; mt < 4; ++mt) a1[mt] = *(short8*)&Wt[1][g][(wr + mt * 16 + c) * 8];
#pragma unroll
            for (int nt = 0; nt < 4; ++nt) b1[nt] = *(short8*)&Xt[1][g][(wc + nt * 16 + c) * 8];
#pragma unroll
            for (int mt = 0; mt < 4; ++mt)
#pragma unroll
                for (int nt = 0; nt < 4; ++nt) {
                    acc[mt][nt] = __builtin_amdgcn_mfma_f32_16x16x32_bf16(a0[mt], b0[nt], acc[mt][nt], 0, 0, 0);
                    acc[mt][nt] = __builtin_amdgcn_mfma_f32_16x16x32_bf16(a0[mt], b1[nt], acc[mt][nt], 0, 0, 0);
                    acc[mt][nt] = __builtin_amdgcn_mfma_f32_16x16x32_bf16(a1[mt], b0[nt], acc[mt][nt], 0, 0, 0);
                }
        } else {
#pragma unroll
            for (int mt = 0; mt < 4; ++mt)
#pragma unroll
                for (int nt = 0; nt < 4; ++nt)
                    acc[mt][nt] = __builtin_amdgcn_mfma_f32_16x16x32_bf16(a0[mt], b0[nt], acc[mt][nt], 0, 0, 0);
        }
    }

#pragma unroll
    for (int mt = 0; mt < 4; ++mt) {
#pragma unroll
        for (int r = 0; r < 4; ++r) {
            int oo = o0 + wr + mt * 16 + g * 4 + r;
            size_t rowbase = ((size_t)n * O + oo) * L_S;
#pragma unroll
            for (int nt = 0; nt < 4; ++nt) {
                int ll = l0 + wc + nt * 16 + c;
                if (OUT_BF16)
                    ((unsigned short*)Y)[rowbase + ll] = bf16_rn(acc[mt][nt][r]);
                else
                    ((float*)Y)[rowbase + ll] = acc[mt][nt][r];
            }
        }
    }
}

// ---------------------------------------------------------------------------
// Fused dwconv + l2norm + pack for Q/K heads (unchanged).
// ---------------------------------------------------------------------------
__global__ __launch_bounds__(256) void fused_qk2(const unsigned short* __restrict__ qkv_bf,
                                                 const float* __restrict__ w_dw,
                                                 unsigned short* __restrict__ Qb,
                                                 unsigned short* __restrict__ Kb) {
    __shared__ unsigned short rows[64 * 264];
    __shared__ float wsm[192];
    const int tid = threadIdx.x;
    const int l0  = blockIdx.x * 256;
    const int gg  = blockIdx.y;
    const int n   = blockIdx.z;
    const int head = gg & 7;
    const int ch0  = (gg < 8) ? head * 64 : 512 + head * 64;

    if (tid < 192) wsm[tid] = w_dw[ch0 * 3 + tid];

    const unsigned short* base = qkv_bf + ((size_t)n * C3 + ch0) * L_S;
    for (int f = tid; f < 2048; f += 256) {
        int e = f >> 5, s = f & 31;
        *(uint4*)&rows[e * 264 + s * 8] = *(const uint4*)&base[(size_t)e * L_S + l0 + s * 8];
    }
    if (tid < 64) {
        rows[tid * 264 + 256] = (l0 > 0) ? base[(size_t)tid * L_S + l0 - 1] : (unsigned short)0;
    } else if (tid < 128) {
        int e = tid - 64;
        rows[e * 264 + 257] = (l0 + 256 < L_S) ? base[(size_t)e * L_S + l0 + 256] : (unsigned short)0;
    }
    __syncthreads();

    const int lL = tid;
    const int iL = (lL == 0)   ? 256 : lL - 1;
    const int iR = (lL == 255) ? 257 : lL + 1;
    float y[64];
    float s = 0.f;
#pragma unroll
    for (int e = 0; e < 64; ++e) {
        float a = bf16_f(rows[e * 264 + iL]);
        float b = bf16_f(rows[e * 264 + lL]);
        float d = bf16_f(rows[e * 264 + iR]);
        float v = wsm[e * 3 + 0] * a + wsm[e * 3 + 1] * b + wsm[e * 3 + 2] * d;
        y[e] = v;
        s += v * v;
    }
    float sc = 1.0f / fmaxf(sqrtf(s), 1e-12f);

    const int l = l0 + tid;
    unsigned short* dst = ((gg < 8) ? Qb : Kb) + (size_t)(n * H_N + head) * 8 * L_S * 8;
#pragma unroll
    for (int p = 0; p < 8; ++p) {
        uint4 pk = make_uint4(pk_bf16(y[8 * p + 0] * sc, y[8 * p + 1] * sc),
                              pk_bf16(y[8 * p + 2] * sc, y[8 * p + 3] * sc),
                              pk_bf16(y[8 * p + 4] * sc, y[8 * p + 5] * sc),
                              pk_bf16(y[8 * p + 6] * sc, y[8 * p + 7] * sc));
        *(uint4*)&dst[((size_t)p * L_S + l) * 8] = pk;
    }
}

// ---------------------------------------------------------------------------
// Fused dwconv + pack for V heads (unchanged).
// ---------------------------------------------------------------------------
__global__ __launch_bounds__(256) void fused_v2(const unsigned short* __restrict__ qkv_bf,
                                                const float* __restrict__ w_dw,
                                                unsigned short* __restrict__ Vb) {
    const int tid = threadIdx.x;
    const int e   = tid & 63;
    const int jp  = blockIdx.x * 4 + (tid >> 6);
    const int h   = blockIdx.y;
    const int n   = blockIdx.z;
    const int ch  = 1024 + h * 64 + e;
    const unsigned short* row = qkv_bf + ((size_t)n * C3 + ch) * L_S;
    const int k0 = jp * 8;

    uint4 mv = *(const uint4*)&row[k0];
    unsigned int lw = (jp > 0)   ? *(const unsigned int*)&row[k0 - 2] : 0u;
    unsigned int rw = (jp < 255) ? *(const unsigned int*)&row[k0 + 8] : 0u;

    float v[10];
    v[0] = bf16_f((unsigned short)(lw >> 16));
    v[1] = bf16_f((unsigned short)(mv.x & 0xFFFF));
    v[2] = bf16_f((unsigned short)(mv.x >> 16));
    v[3] = bf16_f((unsigned short)(mv.y & 0xFFFF));
    v[4] = bf16_f((unsigned short)(mv.y >> 16));
    v[5] = bf16_f((unsigned short)(mv.z & 0xFFFF));
    v[6] = bf16_f((unsigned short)(mv.z >> 16));
    v[7] = bf16_f((unsigned short)(mv.w & 0xFFFF));
    v[8] = bf16_f((unsigned short)(mv.w >> 16));
    v[9] = bf16_f((unsigned short)(rw & 0xFFFF));

    float w0 = w_dw[ch * 3 + 0], w1 = w_dw[ch * 3 + 1], w2 = w_dw[ch * 3 + 2];
    unsigned int o[4];
#pragma unroll
    for (int i = 0; i < 4; ++i) {
        float y0 = w0 * v[2 * i + 0] + w1 * v[2 * i + 1] + w2 * v[2 * i + 2];
        float y1 = w0 * v[2 * i + 1] + w1 * v[2 * i + 2] + w2 * v[2 * i + 3];
        o[i] = pk_bf16(y0, y1);
    }
    uint4 ov = make_uint4(o[0], o[1], o[2], o[3]);
    *(uint4*)&Vb[(((size_t)(n * H_N + h) * 256 + jp) * 512) + e * 8] = ov;
}

// ---------------------------------------------------------------------------
// Flash attention v7: 512 threads = 2 key-split groups x 4 waves.
// Fixed-max softmax is linear in keys -> group A does even 64-key chunks,
// group B odd chunks, each with private 32KB KV dbuf; merge via LDS at end.
// 2 blocks/CU x 8 waves = 16 waves/CU (4/SIMD), 2x attn6.
// grid: (L/128, H, N).
// ---------------------------------------------------------------------------
__global__ __launch_bounds__(512, 4) void attn7(const unsigned short* __restrict__ Qb,
                                                const unsigned short* __restrict__ Kb,
                                                const unsigned short* __restrict__ Vb,
                                                const float* __restrict__ temp,
                                                unsigned short* __restrict__ aoT_hi,
                                                unsigned short* __restrict__ aoT_lo) {
    __shared__ unsigned short KV[32768];   // 64KB: group g2 region at g2*16384; each: buf(cur)=cur*8192 {K 8KB, V 8KB}
    __shared__ float smA[128], smB[128];
    float* OtB = (float*)(KV + 16384);     // group B raw-acc dump (32KB over gB region, post-loop)
    float* OtA = (float*)KV;               // normalized output staging (gA region, post-merge)

    const int tid  = threadIdx.x;
    const int lane = tid & 63;
    const int w    = tid >> 6;     // 0..7
    const int g2   = w >> 2;       // key-split group
    const int wv   = w & 3;        // wave within group
    const int c32  = lane & 31;
    const int h    = lane >> 5;
    const int q0   = blockIdx.x * 128;
    const int hd   = blockIdx.y;
    const int n    = blockIdx.z;

    const size_t hb = (size_t)(n * H_N + hd);
    const unsigned short* Qh = Qb + hb * 8 * L_S * 8;
    const unsigned short* Kh = Kb + hb * 8 * L_S * 8;
    const unsigned short* Vh = Vb + hb * 256 * 512;
    const float t    = temp[hd];
    const float negm = -fabsf(t);

    unsigned short* myKV = KV + g2 * 16384;
    unsigned short* Qs   = KV + 24576;     // gB buf1; consumed before gB's first prefetch lands

    // ---- prologue: 48 gll16 tasks over 8 waves (Q 16, chunk0 K/V 16, chunk1 K/V 16)
    for (int tk = w; tk < 48; tk += 8) {
        if (tk < 16) {
            int p = tk >> 1, hh = tk & 1;
            gll16(Qh + ((size_t)p * L_S + q0 + hh * 64 + lane) * 8, Qs + p * 1024 + hh * 512);
        } else if (tk < 24) {
            int p = tk - 16;
            gll16(Kh + ((size_t)p * L_S + lane) * 8, KV + p * 512);
        } else if (tk < 32) {
            int p = tk - 24;
            gll16(Vh + ((size_t)p * 512 + lane * 8), KV + 4096 + p * 512);
        } else if (tk < 40) {
            int p = tk - 32;
            gll16(Kh + ((size_t)p * L_S + 64 + lane) * 8, KV + 16384 + p * 512);
        } else {
            int p = tk - 40;
            gll16(Vh + ((size_t)(8 + p) * 512 + lane * 8), KV + 16384 + 4096 + p * 512);
        }
    }
    __syncthreads();

    short8 qa[4];
#pragma unroll
    for (int es = 0; es < 4; ++es)
        qa[es] = *(short8*)&Qs[(es * 2 + h) * 1024 + (wv * 32 + c32) * 8];
    __syncthreads();   // qa reads done before first prefetch overwrites Qs

    f32x16 acc0, acc1;
#pragma unroll
    for (int i = 0; i < 16; ++i) { acc0[i] = 0.f; acc1[i] = 0.f; }
    float sumP = 0.f;

    for (int it = 0; it < 16; ++it) {
        const int cur = it & 1;
        const unsigned short* B = myKV + cur * 8192;

        if (it < 15) {   // prefetch this group's next chunk
            const int kb = ((it + 1) * 2 + g2) * 64;
            unsigned short* D = myKV + (cur ^ 1) * 8192;
            gll16(Kh + ((size_t)wv * L_S + kb + lane) * 8,            D + wv * 512);
            gll16(Kh + ((size_t)(wv + 4) * L_S + kb + lane) * 8,      D + (wv + 4) * 512);
            gll16(Vh + ((size_t)(kb / 8 + wv) * 512 + lane * 8),      D + 4096 + wv * 512);
            gll16(Vh + ((size_t)(kb / 8 + wv + 4) * 512 + lane * 8),  D + 4096 + (wv + 4) * 512);
        }

        // ---- S^T = K Q^T
        f32x16 sf0, sf1;
#pragma unroll
        for (int i = 0; i < 16; ++i) { sf0[i] = 0.f; sf1[i] = 0.f; }
#pragma unroll
        for (int es = 0; es < 4; ++es) {
            short8 ka0 = *(short8*)&B[(es * 2 + h) * 512 + c32 * 8];
            short8 ka1 = *(short8*)&B[(es * 2 + h) * 512 + (32 + c32) * 8];
            sf0 = __builtin_amdgcn_mfma_f32_32x32x16_bf16(ka0, qa[es], sf0, 0, 0, 0);
            sf1 = __builtin_amdgcn_mfma_f32_32x32x16_bf16(ka1, qa[es], sf1, 0, 0, 0);
        }

        // ---- softmax (fixed-max, lane-local) + in-register P assembly
        short8 pa[4];
        {
            unsigned int W_[16], R_[16];
#pragma unroll
            for (int G = 0; G < 4; ++G) {
                float p0 = __expf(fmaf(sf0[4*G+0], t, negm));
                float p1 = __expf(fmaf(sf0[4*G+1], t, negm));
                float p2 = __expf(fmaf(sf0[4*G+2], t, negm));
                float p3 = __expf(fmaf(sf0[4*G+3], t, negm));
                sumP += (p0 + p1) + (p2 + p3);
                W_[2*G]   = pk_bf16(p0, p1);
                W_[2*G+1] = pk_bf16(p2, p3);
                float u0 = __expf(fmaf(sf1[4*G+0], t, negm));
                float u1 = __expf(fmaf(sf1[4*G+1], t, negm));
                float u2 = __expf(fmaf(sf1[4*G+2], t, negm));
                float u3 = __expf(fmaf(sf1[4*G+3], t, negm));
                sumP += (u0 + u1) + (u2 + u3);
                W_[8+2*G]   = pk_bf16(u0, u1);
                W_[8+2*G+1] = pk_bf16(u2, u3);
            }
#pragma unroll
            for (int j = 0; j < 16; ++j) R_[j] = __shfl_xor(W_[j], 32);
#pragma unroll
            for (int ks = 0; ks < 4; ++ks) {
                const int bb = (ks >> 1) * 8;
                const int m4 = (ks & 1) * 4;
                unsigned int a0 = h ? R_[bb+m4+2] : W_[bb+m4+0];
                unsigned int a1 = h ? R_[bb+m4+3] : W_[bb+m4+1];
                unsigned int a2 = h ? W_[bb+m4+2] : R_[bb+m4+0];
                unsigned int a3 = h ? W_[bb+m4+3] : R_[bb+m4+1];
                uint4 pu = make_uint4(a0, a1, a2, a3);
                pa[ks] = *(short8*)&pu;
            }
        }

        // ---- O += P V
#pragma unroll
        for (int ks = 0; ks < 4; ++ks) {
            short8 vb0 = *(short8*)&B[4096 + (ks * 2 + h) * 512 + c32 * 8];
            short8 vb1 = *(short8*)&B[4096 + (ks * 2 + h) * 512 + (32 + c32) * 8];
            acc0 = __builtin_amdgcn_mfma_f32_32x32x16_bf16(pa[ks], vb0, acc0, 0, 0, 0);
            acc1 = __builtin_amdgcn_mfma_f32_32x32x16_bf16(pa[ks], vb1, acc1, 0, 0, 0);
        }

        __syncthreads();   // drains prefetch + protects buffer swap (uniform across groups)
    }

    // ---- merge: combine key-halves
    sumP += __shfl_xor(sumP, 32);

    if (g2 == 1) {
        smB[wv * 32 + c32] = sumP;
#pragma unroll
        for (int r = 0; r < 16; ++r) {
            int ql = (r & 3) + 8 * (r >> 2) + 4 * h;
            int qg = wv * 32 + ql;
            OtB[qg * 64 + c32]      = acc0[r];
            OtB[qg * 64 + 32 + c32] = acc1[r];
        }
    } else {
        smA[wv * 32 + c32] = sumP;
    }
    __syncthreads();

    if (g2 == 0) {
#pragma unroll
        for (int r = 0; r < 16; ++r) {
            int ql = (r & 3) + 8 * (r >> 2) + 4 * h;
            int qg = wv * 32 + ql;
            float inv = 1.0f / (smA[qg] + smB[qg]);
            float v0 = (acc0[r] + OtB[qg * 64 + c32])      * inv;
            float v1 = (acc1[r] + OtB[qg * 64 + 32 + c32]) * inv;
            OtA[qg * 64 + (c32 ^ (qg & 31))]        = v0;
            OtA[qg * 64 + ((32 + c32) ^ (qg & 31))] = v1;
        }
    }
    __syncthreads();

    // ---- transposed output: aoT[n][l][d]
    for (int tt = tid; tt < 8192; tt += 512) {
        int qq = tt >> 6, e = tt & 63;
        float v = OtA[qq * 64 + (e ^ (qq & 31))];
        unsigned short hi_ = bf16_rn(v);
        unsigned short lo_ = bf16_rn(v - bf16_f(hi_));
        size_t off = ((size_t)n * L_S + q0 + qq) * D_F + hd * 64 + e;
        aoT_hi[off] = hi_;
        aoT_lo[off] = lo_;
    }
}

// ---------------------------------------------------------------------------
extern "C" void kernel_launch(void* const* d_in, const int* in_sizes, int n_in,
                              void* d_out, int out_size, void* d_ws, size_t ws_size,
                              hipStream_t stream) {
    const float* x      = (const float*)d_in[0];   // (4, 512, 2048)
    const float* w_qkv  = (const float*)d_in[1];   // (1536, 512)
    const float* w_dw   = (const float*)d_in[2];   // (1536, 3)
    const float* w_proj = (const float*)d_in[3];   // (512, 512)
    const float* temp   = (const float*)d_in[4];   // (8)
    float* out = (float*)d_out;

    const size_t WQE = (size_t)C3 * D_F;           // 786,432
    const size_t WPE = (size_t)D_F * D_F;          // 262,144

    char* ws = (char*)d_ws;
    unsigned short* qkv_bf = (unsigned short*)ws;               // 25,165,824 B
    unsigned short* Qb     = (unsigned short*)(ws + 25165824);  //  8,388,608 B
    unsigned short* Kb     = (unsigned short*)(ws + 33554432);  //  8,388,608 B
    unsigned short* Vb     = (unsigned short*)(ws + 41943040);  //  8,388,608 B
    unsigned short* xT     = (unsigned short*)(ws + 50331648);  //  8,388,608 B
    unsigned short* aoT_lo = (unsigned short*)(ws + 58720256);  //  8,388,608 B
    unsigned short* wq_hi  = (unsigned short*)(ws + 67108864);  //  1,572,864 B
    unsigned short* wq_lo  = wq_hi + WQE;
    unsigned short* wp_hi  = (unsigned short*)(ws + 70254592);  //    524,288 B
    unsigned short* wp_lo  = wp_hi + WPE;                       // ends ~71.3 MB
    unsigned short* aoT_hi = xT;   // reuse: xT consumed by QKV gemm before attn writes

    // 0) weight splits + x transpose/convert
    cvt_xT<<<dim3(L_S / 64, D_F / 64, N_B), 256, 0, stream>>>(x, xT, D_F);
    cvt_split<<<dim3((WQE / 4 + 255) / 256), 256, 0, stream>>>(w_qkv, wq_hi, wq_lo, WQE / 4);
    cvt_split<<<dim3((WPE / 4 + 255) / 256), 256, 0, stream>>>(w_proj, wp_hi, wp_lo, WPE / 4);

    // 1) QKV 1x1 conv: bf16 MFMA, gll16-staged -> bf16
    gemm_mfma2<0, 1><<<dim3(L_S / 128, C3 / 128, N_B), 256, 0, stream>>>(
        wq_hi, nullptr, xT, nullptr, qkv_bf, C3, D_F);

    // 2) fused dwconv (+l2norm) + MFMA-layout bf16 pack
    fused_qk2<<<dim3(L_S / 256, 16, N_B), 256, 0, stream>>>(qkv_bf, w_dw, Qb, Kb);
    fused_v2<<<dim3(64, H_N, N_B), 256, 0, stream>>>(qkv_bf, w_dw, Vb);

    // 3) attention (key-split 8-wave blocks) -> transposed split bf16 hi/lo
    attn7<<<dim3(L_S / 128, H_N, N_B), 512, 0, stream>>>(Qb, Kb, Vb, temp, aoT_hi, aoT_lo);

    // 4) 3-term split-bf16 proj GEMM (gll16-staged) -> fp32 out
    gemm_mfma2<1, 0><<<dim3(L_S / 128, D_F / 128, N_B), 256, 0, stream>>>(
        wp_hi, wp_lo, aoT_hi, aoT_lo, out, D_F, D_F);
}